// Round 18
// baseline (359.674 us; speedup 1.0000x reference)
//
#include <hip/hip_runtime.h>
#include <stdint.h>

#define DEV __device__ __forceinline__

typedef __attribute__((ext_vector_type(8))) short bf16x8;   // 8 bf16 = 4 VGPRs
typedef __attribute__((ext_vector_type(4))) float f32x4;

// ---------- bf16 bit helpers ----------
DEV float bf2f(uint16_t u) { return __uint_as_float(((uint32_t)u) << 16); }
DEV uint16_t f2bfbits(float f) {          // round-to-nearest-even
    uint32_t x = __float_as_uint(f);
    uint32_t r = x + 0x7fffu + ((x >> 16) & 1u);
    return (uint16_t)(r >> 16);
}
DEV void stv(uint16_t* p, float v) { *p = f2bfbits(v); }
DEV void stv(float* p, float v) { *p = v; }

template<int C> DEV void ldbf(const uint16_t* p, float* f);
template<> DEV void ldbf<8>(const uint16_t* p, float* f) {
    uint4 v = *reinterpret_cast<const uint4*>(p);
    f[0] = __uint_as_float(v.x << 16); f[1] = __uint_as_float(v.x & 0xffff0000u);
    f[2] = __uint_as_float(v.y << 16); f[3] = __uint_as_float(v.y & 0xffff0000u);
    f[4] = __uint_as_float(v.z << 16); f[5] = __uint_as_float(v.z & 0xffff0000u);
    f[6] = __uint_as_float(v.w << 16); f[7] = __uint_as_float(v.w & 0xffff0000u);
}

// async global->LDS, 16B per lane; LDS dest = wave-uniform base + lane*16
DEV void gl16(const uint16_t* g, uint8_t* l) {
    __builtin_amdgcn_global_load_lds(
        (const __attribute__((address_space(1))) uint32_t*)g,
        (__attribute__((address_space(3))) uint32_t*)l, 16, 0, 0);
}

// counted vmcnt wait (compile-time literal; lgkm/exp untouched)
template<int N> DEV void vwait() {
    if constexpr (N == 0)      asm volatile("s_waitcnt vmcnt(0)" ::: "memory");
    else if constexpr (N == 3) asm volatile("s_waitcnt vmcnt(3)" ::: "memory");
    else if constexpr (N == 4) asm volatile("s_waitcnt vmcnt(4)" ::: "memory");
    else if constexpr (N == 6) asm volatile("s_waitcnt vmcnt(6)" ::: "memory");
    else                       asm volatile("s_waitcnt vmcnt(0)" ::: "memory");
}

// ---------------------- CSR build ----------------------
__global__ void k_count(const int* __restrict__ dst, int e, int* __restrict__ deg) {
    int i = blockIdx.x * 256 + threadIdx.x;
    if (i < e) atomicAdd(&deg[dst[i]], 1);
}

__global__ void k_block_sums(const int* __restrict__ deg, int n, int* __restrict__ bsum) {
    __shared__ int sm[256];
    int base = blockIdx.x * 1024;
    int s = 0;
    for (int i = threadIdx.x; i < 1024; i += 256) {
        int g = base + i;
        if (g < n) s += deg[g];
    }
    sm[threadIdx.x] = s; __syncthreads();
    for (int o = 128; o > 0; o >>= 1) {
        if (threadIdx.x < o) sm[threadIdx.x] += sm[threadIdx.x + o];
        __syncthreads();
    }
    if (threadIdx.x == 0) bsum[blockIdx.x] = sm[0];
}

__global__ void k_scan_bsums(int* bsum, int nb) {
    __shared__ int sm[256];
    int t = threadIdx.x;
    int v = (t < nb) ? bsum[t] : 0;
    sm[t] = v; __syncthreads();
    for (int o = 1; o < 256; o <<= 1) {
        int add = (t >= o) ? sm[t - o] : 0;
        __syncthreads();
        sm[t] += add;
        __syncthreads();
    }
    if (t < nb) bsum[t] = (t == 0) ? 0 : sm[t - 1];
}

__global__ void k_scan_final(const int* __restrict__ deg, int n,
                             const int* __restrict__ bsum, int* __restrict__ offs,
                             int* __restrict__ cursor) {
    __shared__ int sm[256];
    int t = threadIdx.x;
    int i0 = blockIdx.x * 1024 + t * 4;
    int d0 = (i0     < n) ? deg[i0]     : 0;
    int d1 = (i0 + 1 < n) ? deg[i0 + 1] : 0;
    int d2 = (i0 + 2 < n) ? deg[i0 + 2] : 0;
    int d3 = (i0 + 3 < n) ? deg[i0 + 3] : 0;
    int ts = d0 + d1 + d2 + d3;
    sm[t] = ts; __syncthreads();
    for (int o = 1; o < 256; o <<= 1) {
        int add = (t >= o) ? sm[t - o] : 0;
        __syncthreads();
        sm[t] += add;
        __syncthreads();
    }
    int e0 = bsum[blockIdx.x] + ((t == 0) ? 0 : sm[t - 1]);
    int e1 = e0 + d0, e2 = e1 + d1, e3 = e2 + d2, e4 = e3 + d3;
    if (i0     < n) { offs[i0]     = e0; cursor[i0]     = e0; }
    if (i0 + 1 < n) { offs[i0 + 1] = e1; cursor[i0 + 1] = e1; }
    if (i0 + 2 < n) { offs[i0 + 2] = e2; cursor[i0 + 2] = e2; }
    if (i0 + 3 < n) { offs[i0 + 3] = e3; cursor[i0 + 3] = e3; }
    if (i0 <= n - 1 && n - 1 < i0 + 4) offs[n] = e4;  // total
}

__global__ void k_scatter(const int* __restrict__ src, const int* __restrict__ dst, int e,
                          int* __restrict__ cursor, int* __restrict__ csr) {
    int i = blockIdx.x * 256 + threadIdx.x;
    if (i < e) {
        int p = atomicAdd(&cursor[dst[i]], 1);
        csr[p] = src[i];
    }
}

// ---------------------- fp32 -> bf16 convert ----------------------
__global__ void k_f2b(const float* __restrict__ in, uint16_t* __restrict__ o, int n4) {
    int i = blockIdx.x * 256 + threadIdx.x;
    if (i < n4) {
        float4 v = reinterpret_cast<const float4*>(in)[i];
        uint2 w;
        w.x = f2bfbits(v.x) | ((uint32_t)f2bfbits(v.y) << 16);
        w.y = f2bfbits(v.z) | ((uint32_t)f2bfbits(v.w) << 16);
        reinterpret_cast<uint2*>(o)[i] = w;
    }
}

// ---------------------- fused weight prep -> PACKED layout ----------------------
// packed[p][c][j] = W^T[c][p*8+j]  (p = k-plane = k/8, c = output col, j = k%8)
struct PrepSeg { const float* W; uint16_t* wt; int K, Dreal, ncols, koff, noff, Dtot, start, end; };
struct PrepAll { PrepSeg s[8]; };

__global__ void k_prep_all(PrepAll P, int total) {
    int idx = blockIdx.x * 256 + threadIdx.x;
    if (idx >= total) return;
#pragma unroll
    for (int i = 0; i < 8; ++i) {
        if (idx >= P.s[i].start && idx < P.s[i].end) {
            int loc = idx - P.s[i].start;
            int K = P.s[i].K;
            int nn = loc / K, k = loc - nn * K;
            float v = (nn < P.s[i].Dreal) ? P.s[i].W[(size_t)k * P.s[i].Dreal + nn] : 0.f;
            int c = P.s[i].noff + nn;
            int kk = P.s[i].koff + k;
            P.s[i].wt[((size_t)(kk >> 3) * P.s[i].Dtot + c) * 8 + (kk & 7)] = f2bfbits(v);
        }
    }
}

// ---------------------- max-aggregation, D=128: 4 nodes/wave, 16B/lane gathers ----------------------
__global__ __launch_bounds__(256) void k_aggr_max(const uint16_t* __restrict__ X,
                                                  const int* __restrict__ offs,
                                                  const int* __restrict__ csr,
                                                  int n, uint16_t* __restrict__ out) {
    int sl = threadIdx.x & 15;
    int node = blockIdx.x * 16 + (threadIdx.x >> 4);
    if (node >= n) return;
    int beg = offs[node], end = offs[node + 1];
    float acc[8] = {};
    const size_t loff = (size_t)sl * 8;
    int i = beg;
    for (; i + 3 < end; i += 4) {
        int s0 = csr[i], s1 = csr[i + 1], s2 = csr[i + 2], s3 = csr[i + 3];
        float f0[8], f1[8], f2[8], f3[8];
        ldbf<8>(X + (size_t)s0 * 128 + loff, f0);
        ldbf<8>(X + (size_t)s1 * 128 + loff, f1);
        ldbf<8>(X + (size_t)s2 * 128 + loff, f2);
        ldbf<8>(X + (size_t)s3 * 128 + loff, f3);
#pragma unroll
        for (int c = 0; c < 8; c++)
            acc[c] = fmaxf(acc[c], fmaxf(fmaxf(f0[c], f1[c]), fmaxf(f2[c], f3[c])));
    }
    for (; i < end; ++i) {
        int s = csr[i];
        float f[8];
        ldbf<8>(X + (size_t)s * 128 + loff, f);
#pragma unroll
        for (int c = 0; c < 8; c++) acc[c] = fmaxf(acc[c], f[c]);
    }
    uint4 v;
    v.x = f2bfbits(acc[0]) | ((uint32_t)f2bfbits(acc[1]) << 16);
    v.y = f2bfbits(acc[2]) | ((uint32_t)f2bfbits(acc[3]) << 16);
    v.z = f2bfbits(acc[4]) | ((uint32_t)f2bfbits(acc[5]) << 16);
    v.w = f2bfbits(acc[6]) | ((uint32_t)f2bfbits(acc[7]) << 16);
    *reinterpret_cast<uint4*>(out + (size_t)node * 128 + loff) = v;
}

// ---------------------- mean-aggregate(Y) + Z + LN + ReLU, 4 nodes/wave, 16B/lane ----------------------
__global__ __launch_bounds__(256) void k_aggr_ln(const uint16_t* __restrict__ YZ,
                                                 const int* __restrict__ offs,
                                                 const int* __restrict__ csr,
                                                 const float* __restrict__ g,
                                                 const float* __restrict__ b,
                                                 int n, uint16_t* __restrict__ out) {
    int sl = threadIdx.x & 15;
    int node = blockIdx.x * 16 + (threadIdx.x >> 4);
    if (node >= n) return;
    int beg = offs[node], end = offs[node + 1];
    float a[8] = {};
    const size_t loff = (size_t)sl * 8;
    int i = beg;
    for (; i + 3 < end; i += 4) {
        int s0 = csr[i], s1 = csr[i + 1], s2 = csr[i + 2], s3 = csr[i + 3];
        float f0[8], f1[8], f2[8], f3[8];
        ldbf<8>(YZ + (size_t)s0 * 256 + loff, f0);
        ldbf<8>(YZ + (size_t)s1 * 256 + loff, f1);
        ldbf<8>(YZ + (size_t)s2 * 256 + loff, f2);
        ldbf<8>(YZ + (size_t)s3 * 256 + loff, f3);
#pragma unroll
        for (int c = 0; c < 8; c++) a[c] += (f0[c] + f1[c]) + (f2[c] + f3[c]);
    }
    for (; i < end; ++i) {
        int s = csr[i];
        float f[8];
        ldbf<8>(YZ + (size_t)s * 256 + loff, f);
#pragma unroll
        for (int c = 0; c < 8; c++) a[c] += f[c];
    }
    int d = end - beg; if (d < 1) d = 1;
    float scale = 1.f / (float)d;
    float z[8];
    ldbf<8>(YZ + (size_t)node * 256 + 128 + loff, z);
    float v[8];
#pragma unroll
    for (int c = 0; c < 8; c++) v[c] = a[c] * scale + z[c];
    float s = 0.f, s2 = 0.f;
#pragma unroll
    for (int c = 0; c < 8; c++) { s += v[c]; s2 += v[c] * v[c]; }
#pragma unroll
    for (int o = 1; o < 16; o <<= 1) { s += __shfl_xor(s, o); s2 += __shfl_xor(s2, o); }
    float mean = s * (1.f / 128.f);
    float var = s2 * (1.f / 128.f) - mean * mean;
    float inv = rsqrtf(var + 1e-5f);
    float y[8];
#pragma unroll
    for (int c = 0; c < 8; c++)
        y[c] = fmaxf((v[c] - mean) * inv * g[loff + c] + b[loff + c], 0.f);
    uint4 w;
    w.x = f2bfbits(y[0]) | ((uint32_t)f2bfbits(y[1]) << 16);
    w.y = f2bfbits(y[2]) | ((uint32_t)f2bfbits(y[3]) << 16);
    w.z = f2bfbits(y[4]) | ((uint32_t)f2bfbits(y[5]) << 16);
    w.w = f2bfbits(y[6]) | ((uint32_t)f2bfbits(y[7]) << 16);
    *reinterpret_cast<uint4*>(out + (size_t)node * 128 + loff) = w;
}

// ---------------------- MFMA GEMM: A panel resident (contiguous 1KB gl16, XOR-swizzled) ----------------------
// block = 64 rows x 256 cols; 4 waves of 16 rows x 256 cols (acc[16] = 64 VGPR).
// A panel (whole rows, 16/32KB) staged ONCE as contiguous 1KB chunks; LDS linear row-major,
// source col pre-swizzled colb ^= ((row&7)<<4); fragment reads apply the same XOR (rule #21).
// W packed (R17) -> contiguous 1KB chunks, triple-buffered, counted-vmcnt pipeline (L=4, W-only).
// A frag: row=lane&15, k=(lane>>4)*8+j ; B frag: col=lane&15 ; C/D: col=lane&15, row=(lane>>4)*4+reg.
template<int KPER, int DOUT, bool DUAL, bool LN, bool ZBIAS, typename TO>
__global__ __launch_bounds__(256) void k_mf(const uint16_t* __restrict__ A0,
                                            const uint16_t* __restrict__ A1,
                                            const uint16_t* __restrict__ WT,
                                            const float* __restrict__ bias,
                                            const float* __restrict__ g,
                                            const float* __restrict__ bvec,
                                            int n, TO* __restrict__ out) {
    constexpr int DB = 256;
    constexpr int KEFF = KPER * (DUAL ? 2 : 1);
    constexpr int NST = KEFF / 32;        // k-steps
    constexpr int NF = DB / 16;           // 16 col-quads
    constexpr int WPL = DB * 16;          // W plane bytes per 8-k chunk (4KB)
    constexpr int WB = DB * 64;           // W tile bytes per 32-k step (16KB)
    constexpr int HB = DB / 64;           // W 1KB-chunks per wave per stage (4)
    constexpr int RB = KPER * 2;          // A row bytes (256 or 512)
    constexpr int PAN = 64 * RB;          // one A panel (16KB or 32KB)
    constexpr int PCH = PAN / 1024;       // chunks per panel (16 or 32)
    constexpr int NPAN = DUAL ? 2 : 1;
    __shared__ __align__(16) uint8_t aP[NPAN * PAN];
    __shared__ __align__(16) uint8_t wL[3][WB];

    int tid = threadIdx.x;
    int lane = tid & 63, wid = tid >> 6;
    int lr = lane & 15, kb = lane >> 4;
    int row0 = blockIdx.x * 64;

    // ---- stage full A panel(s): all-contiguous 1KB chunks, source pre-swizzled ----
    for (int c = wid; c < NPAN * PCH; c += 4) {
        int pan = c / PCH, cc = c % PCH;
        const uint16_t* Asrc = (DUAL && pan) ? A1 : A0;
        int rloc, colb;
        if constexpr (RB == 256) { rloc = cc * 4 + (lane >> 4); colb = (lane & 15) * 16; }
        else                     { rloc = cc * 2 + (lane >> 5); colb = (lane & 31) * 16; }
        int grow = row0 + rloc; if (grow >= n) grow = n - 1;
        gl16((const uint16_t*)((const uint8_t*)Asrc + (size_t)grow * RB + (colb ^ ((rloc & 7) << 4))),
             aP + (size_t)c * 1024);
    }

    // ---- W staging (packed, contiguous) ----
    auto stageW = [&](int kt, uint8_t* buf) {
#pragma unroll
        for (int j = 0; j < HB; ++j) {
            int p = wid * HB + j, cb = p / HB, h = p % HB;
            int plane = (kt >> 3) + cb;
            gl16(WT + ((size_t)plane * DB + h * 64 + lane) * 8, buf + cb * WPL + h * 1024);
        }
    };

    stageW(0, wL[0]);
    if constexpr (NST > 1) stageW(32, wL[1]);
    vwait<0>();                       // drain A panel + W stages 0,1 (one-time)
    __builtin_amdgcn_s_barrier();
    __builtin_amdgcn_sched_barrier(0);

    f32x4 acc[NF] = {};
#pragma unroll
    for (int s = 0; s < NST; ++s) {
        if (s > 0) {                  // stage s readiness (stage s+1 may stay in flight)
            if (s < NST - 1) vwait<4>(); else vwait<0>();
            __builtin_amdgcn_s_barrier();
            __builtin_amdgcn_sched_barrier(0);
        }
        if (s + 2 < NST) stageW((s + 2) * 32, wL[(s + 2) % 3]);
        int kt = s * 32;
        const uint8_t* pan = aP; int kk = kt;
        if (DUAL && kt >= KPER) { pan = aP + PAN; kk = kt - KPER; }
        int ar = wid * 16 + lr;       // LDS panel row
        bf16x8 af = *reinterpret_cast<const bf16x8*>(
            pan + (size_t)ar * RB + (((kk + kb * 8) * 2) ^ ((ar & 7) << 4)));
        const uint8_t* wB = wL[s % 3];
#pragma unroll
        for (int nf = 0; nf < NF; ++nf) {
            bf16x8 wf = *reinterpret_cast<const bf16x8*>(wB + kb * WPL + (nf * 16 + lr) * 16);
            acc[nf] = __builtin_amdgcn_mfma_f32_16x16x32_bf16(af, wf, acc[nf], 0, 0, 0);
        }
    }

    // ---- epilogue: bias (+ LN + ReLU), store ----
#pragma unroll
    for (int nf = 0; nf < NF; ++nf) {
        int col = nf * 16 + lr;
        float bsv;
        if constexpr (ZBIAS) {
            bsv = (col >= DOUT / 2) ? bias[col - DOUT / 2] : 0.f;
        } else {
            bsv = (col < DOUT) ? bias[col] : 0.f;
        }
#pragma unroll
        for (int r = 0; r < 4; ++r) acc[nf][r] += bsv;
    }
    if constexpr (LN) {
        float gv[NF], bv2[NF];
#pragma unroll
        for (int nf = 0; nf < NF; ++nf) {
            int col = nf * 16 + lr;
            gv[nf] = g[col]; bv2[nf] = bvec[col];
        }
        float s[4], s2[4];
#pragma unroll
        for (int r = 0; r < 4; ++r) { s[r] = 0.f; s2[r] = 0.f; }
#pragma unroll
        for (int nf = 0; nf < NF; ++nf)
#pragma unroll
            for (int r = 0; r < 4; ++r) { float v = acc[nf][r]; s[r] += v; s2[r] += v * v; }
#pragma unroll
        for (int r = 0; r < 4; ++r) {
#pragma unroll
            for (int o = 1; o < 16; o <<= 1) {
                s[r] += __shfl_xor(s[r], o);
                s2[r] += __shfl_xor(s2[r], o);
            }
            float mean = s[r] / DOUT;
            float var = s2[r] / DOUT - mean * mean;
            float inv = rsqrtf(var + 1e-5f);
#pragma unroll
            for (int nf = 0; nf < NF; ++nf) {
                float y = (acc[nf][r] - mean) * inv * gv[nf] + bv2[nf];
                acc[nf][r] = fmaxf(y, 0.f);
            }
        }
    }
#pragma unroll
    for (int r = 0; r < 4; ++r) {
        int row = row0 + wid * 16 + kb * 4 + r;
        if (row < n) {
#pragma unroll
            for (int nf = 0; nf < NF; ++nf) {
                int col = nf * 16 + lr;
                if (col < DOUT)
                    stv(out + (size_t)row * DOUT + col, acc[nf][r]);
            }
        }
    }
}

// ---------------------- fused tail: h4 = LN(relu(h3@W4+b4)); out = h4@W5 + b5 ----------------------
// (R17 structure: packed W4/W5, 128-row blocks, proven)
__global__ __launch_bounds__(256) void k_tail(const uint16_t* __restrict__ A,
                                              const uint16_t* __restrict__ WT4,
                                              const float* __restrict__ b4,
                                              const float* __restrict__ g4,
                                              const float* __restrict__ bv4,
                                              const uint16_t* __restrict__ WT5,
                                              const float* __restrict__ b5,
                                              int n, float* __restrict__ out) {
    __shared__ __align__(16) uint8_t lds[3][8192 + 4096];
    __shared__ __align__(16) uint8_t w5L[16384];
    __shared__ __align__(16) uint8_t h4L[16384];

    int tid = threadIdx.x;
    int lane = tid & 63, wid = tid >> 6;
    int lr = lane & 15, kb = lane >> 4;
    int row0 = blockIdx.x * 128;
    int wrow = wid * 32;

    auto stage = [&](int kt, uint8_t* buf) {
        uint8_t* aB = buf;
        uint8_t* wB = buf + 8192;
#pragma unroll
        for (int j = 0; j < 2; ++j) {
            int p = wid * 2 + j, cb = p >> 1, h = p & 1;
            int grow = row0 + h * 64 + lane; if (grow >= n) grow = n - 1;
            gl16(A + (size_t)grow * 128 + kt + cb * 8, aB + cb * 2048 + h * 1024);
        }
        gl16(WT4 + ((size_t)((kt >> 3) + wid) * 64 + lane) * 8, wB + wid * 1024);
    };

#pragma unroll
    for (int j = 0; j < 4; ++j) {
        int p = wid * 4 + j, cb = p >> 1, h = p & 1;
        gl16(WT5 + ((size_t)cb * 128 + h * 64 + lane) * 8, w5L + cb * 2048 + h * 1024);
    }

    f32x4 acc1[2][4] = {};
    stage(0, lds[0]);
    stage(32, lds[1]);

#pragma unroll
    for (int s = 0; s < 4; ++s) {
        if (s < 3) vwait<3>(); else vwait<0>();
        __builtin_amdgcn_s_barrier();
        __builtin_amdgcn_sched_barrier(0);
        if (s + 2 < 4) stage((s + 2) * 32, lds[(s + 2) % 3]);
        const uint8_t* aB = lds[s % 3];
        const uint8_t* wB = lds[s % 3] + 8192;
        bf16x8 af0 = *reinterpret_cast<const bf16x8*>(aB + kb * 2048 + (wrow + lr) * 16);
        bf16x8 af1 = *reinterpret_cast<const bf16x8*>(aB + kb * 2048 + (wrow + 16 + lr) * 16);
#pragma unroll
        for (int nf = 0; nf < 4; ++nf) {
            bf16x8 wf = *reinterpret_cast<const bf16x8*>(wB + kb * 1024 + (nf * 16 + lr) * 16);
            acc1[0][nf] = __builtin_amdgcn_mfma_f32_16x16x32_bf16(af0, wf, acc1[0][nf], 0, 0, 0);
            acc1[1][nf] = __builtin_amdgcn_mfma_f32_16x16x32_bf16(af1, wf, acc1[1][nf], 0, 0, 0);
        }
    }

#pragma unroll
    for (int nf = 0; nf < 4; ++nf) {
        float bsv = b4[nf * 16 + lr];
#pragma unroll
        for (int r = 0; r < 4; ++r) { acc1[0][nf][r] += bsv; acc1[1][nf][r] += bsv; }
    }
    {
        float gv[4], bv2[4];
#pragma unroll
        for (int nf = 0; nf < 4; ++nf) { gv[nf] = g4[nf * 16 + lr]; bv2[nf] = bv4[nf * 16 + lr]; }
#pragma unroll
        for (int m = 0; m < 2; ++m) {
            float s[4] = {}, s2[4] = {};
#pragma unroll
            for (int nf = 0; nf < 4; ++nf)
#pragma unroll
                for (int r = 0; r < 4; ++r) { float v = acc1[m][nf][r]; s[r] += v; s2[r] += v * v; }
#pragma unroll
            for (int r = 0; r < 4; ++r) {
#pragma unroll
                for (int o = 1; o < 16; o <<= 1) { s[r] += __shfl_xor(s[r], o); s2[r] += __shfl_xor(s2[r], o); }
                float mean = s[r] * (1.f / 64.f);
                float var = s2[r] * (1.f / 64.f) - mean * mean;
                float inv = rsqrtf(var + 1e-5f);
#pragma unroll
                for (int nf = 0; nf < 4; ++nf)
                    acc1[m][nf][r] = fmaxf((acc1[m][nf][r] - mean) * inv * gv[nf] + bv2[nf], 0.f);
            }
        }
    }

#pragma unroll
    for (int m = 0; m < 2; ++m)
#pragma unroll
        for (int r = 0; r < 4; ++r) {
            int row = wrow + m * 16 + kb * 4 + r;
#pragma unroll
            for (int nf = 0; nf < 4; ++nf) {
                int col = nf * 16 + lr;
                *reinterpret_cast<uint16_t*>(h4L + ((col >> 3) * 2048 + row * 16 + (col & 7) * 2)) =
                    f2bfbits(acc1[m][nf][r]);
            }
        }
    __syncthreads();

    f32x4 acc2[2][8] = {};
#pragma unroll
    for (int s = 0; s < 2; ++s) {
        bf16x8 af0 = *reinterpret_cast<const bf16x8*>(h4L + (s * 4 + kb) * 2048 + (wrow + lr) * 16);
        bf16x8 af1 = *reinterpret_cast<const bf16x8*>(h4L + (s * 4 + kb) * 2048 + (wrow + 16 + lr) * 16);
#pragma unroll
        for (int nf = 0; nf < 8; ++nf) {
            bf16x8 wf = *reinterpret_cast<const bf16x8*>(w5L + (s * 4 + kb) * 2048 + (nf * 16 + lr) * 16);
            acc2[0][nf] = __builtin_amdgcn_mfma_f32_16x16x32_bf16(af0, wf, acc2[0][nf], 0, 0, 0);
            acc2[1][nf] = __builtin_amdgcn_mfma_f32_16x16x32_bf16(af1, wf, acc2[1][nf], 0, 0, 0);
        }
    }
#pragma unroll
    for (int m = 0; m < 2; ++m)
#pragma unroll
        for (int r = 0; r < 4; ++r) {
            int row = row0 + wrow + m * 16 + kb * 4 + r;
            if (row < n) {
#pragma unroll
                for (int nf = 0; nf < 8; ++nf) {
                    int col = nf * 16 + lr;
                    if (col < 100)
                        out[(size_t)row * 100 + col] = acc2[m][nf][r] + b5[col];
                }
            }
        }
}

// ---------------------- launcher ----------------------
extern "C" void kernel_launch(void* const* d_in, const int* in_sizes, int n_in,
                              void* d_out, int out_size, void* d_ws, size_t ws_size,
                              hipStream_t stream) {
    const float* x     = (const float*)d_in[0];
    const int*   src   = (const int*)d_in[1];
    const int*   dst   = (const int*)d_in[2];
    const float* s1_wl = (const float*)d_in[3];
    const float* s1_bl = (const float*)d_in[4];
    const float* s1_wr = (const float*)d_in[5];
    const float* ln1_g = (const float*)d_in[6];
    const float* ln1_b = (const float*)d_in[7];
    const float* s2_wl = (const float*)d_in[8];
    const float* s2_bl = (const float*)d_in[9];
    const float* s2_wr = (const float*)d_in[10];
    const float* ln2_g = (const float*)d_in[11];
    const float* ln2_b = (const float*)d_in[12];
    const float* s3_wl = (const float*)d_in[13];
    const float* s3_bl = (const float*)d_in[14];
    const float* s3_wr = (const float*)d_in[15];
    const float* ln3_g = (const float*)d_in[16];
    const float* ln3_b = (const float*)d_in[17];
    const float* l1_w  = (const float*)d_in[18];
    const float* l1_b  = (const float*)d_in[19];
    const float* ln4_g = (const float*)d_in[20];
    const float* ln4_b = (const float*)d_in[21];
    const float* lo_w  = (const float*)d_in[22];
    const float* lo_b  = (const float*)d_in[23];
    float* out = (float*)d_out;

    const int N = in_sizes[0] / 128;
    const int E = in_sizes[1];
    (void)n_in; (void)out_size; (void)ws_size;

    char* w = (char*)d_ws;
    size_t off = 0;
    auto alloc = [&](size_t bytes) -> void* {
        void* p = w + off;
        off = (off + bytes + 255) & ~(size_t)255;
        return p;
    };
    int* deg    = (int*)alloc((size_t)N * 4);
    int* offs   = (int*)alloc((size_t)(N + 1) * 4);
    int* cursor = (int*)alloc((size_t)N * 4);
    int* bsum   = (int*)alloc(1024 * 4);
    int* csr    = (int*)alloc((size_t)E * 4);
    uint16_t* wt1 = (uint16_t*)alloc(256 * 128 * 2);   // packed [16 planes][256 cols][8]
    uint16_t* wt2 = (uint16_t*)alloc(256 * 256 * 2);   // packed [32 planes][256 cols][8]
    uint16_t* wt3 = (uint16_t*)alloc(256 * 256 * 2);   // packed [32 planes][256 cols][8]
    uint16_t* wt4 = (uint16_t*)alloc(64 * 128 * 2);    // packed [16 planes][64 cols][8]
    uint16_t* wt5 = (uint16_t*)alloc(128 * 64 * 2);    // packed [8 planes][128 cols][8]
    uint16_t* xb    = (uint16_t*)alloc((size_t)N * 128 * 2);
    uint16_t* YZ    = (uint16_t*)alloc((size_t)N * 256 * 2);  // [Y|Z] for layers 1 and 3
    uint16_t* h1    = (uint16_t*)alloc((size_t)N * 128 * 2);
    uint16_t* aggrB = (uint16_t*)alloc((size_t)N * 128 * 2);  // max-aggr output
    uint16_t* h2    = (uint16_t*)alloc((size_t)N * 256 * 2);
    uint16_t* h3    = (uint16_t*)alloc((size_t)N * 128 * 2);

    int gE = (E + 255) / 256;
    int nb = (N + 1023) / 1024;
    int gN16 = (N + 15) / 16;
    int g64  = (N + 63) / 64;
    int g128 = (N + 127) / 128;

    // CSR build
    hipMemsetAsync(deg, 0, (size_t)N * 4, stream);
    k_count<<<gE, 256, 0, stream>>>(dst, E, deg);
    k_block_sums<<<nb, 256, 0, stream>>>(deg, N, bsum);
    k_scan_bsums<<<1, 256, 0, stream>>>(bsum, nb);
    k_scan_final<<<nb, 256, 0, stream>>>(deg, N, bsum, offs, cursor);
    k_scatter<<<gE, 256, 0, stream>>>(src, dst, E, cursor, csr);

    // fused weight prep (packed layout)
    PrepAll P;
    int cum = 0;
    auto seg = [&](int i, const float* W, uint16_t* wt, int K, int Dreal, int ncols,
                   int koff, int noff, int Dtot) {
        P.s[i] = {W, wt, K, Dreal, ncols, koff, noff, Dtot, cum, cum + ncols * K};
        cum += ncols * K;
    };
    seg(0, s1_wl, wt1, 128, 128, 128, 0,   0,   256);
    seg(1, s1_wr, wt1, 128, 128, 128, 0,   128, 256);
    seg(2, s2_wl, wt2, 128, 256, 256, 0,   0,   256);
    seg(3, s2_wr, wt2, 128, 256, 256, 128, 0,   256);
    seg(4, s3_wl, wt3, 256, 128, 128, 0,   0,   256);
    seg(5, s3_wr, wt3, 256, 128, 128, 0,   128, 256);
    seg(6, l1_w,  wt4, 128, 64,  64,  0,   0,   64);
    seg(7, lo_w,  wt5, 64,  100, 128, 0,   0,   128);
    k_prep_all<<<(cum + 255) / 256, 256, 0, stream>>>(P, cum);

    // x -> bf16
    k_f2b<<<(N * 128 / 4 + 255) / 256, 256, 0, stream>>>(x, xb, N * 128 / 4);

    // layer 1 (mean, reordered): YZ1 = xb @ [Wl1|Wr1] (+bl on Z half); h1 = LN(mean(Y1)+Z1)
    k_mf<128, 256, false, false, true, uint16_t><<<g64, 256, 0, stream>>>(
        xb, nullptr, wt1, s1_bl, nullptr, nullptr, N, YZ);
    k_aggr_ln<<<gN16, 256, 0, stream>>>(YZ, offs, csr, ln1_g, ln1_b, N, h1);

    // layer 2 (max): aggrB = max-gather(h1); h2 = LN([aggrB|h1] @ wt2 + b2)
    k_aggr_max<<<gN16, 256, 0, stream>>>(h1, offs, csr, N, aggrB);
    k_mf<128, 256, true, true, false, uint16_t><<<g64, 256, 0, stream>>>(
        aggrB, h1, wt2, s2_bl, ln2_g, ln2_b, N, h2);

    // layer 3 (mean, reordered): YZ3 = h2 @ [Wl3|Wr3] (+bl on Z half); h3 = LN(mean(Y3)+Z3)
    k_mf<256, 256, false, false, true, uint16_t><<<g64, 256, 0, stream>>>(
        h2, nullptr, wt3, s3_bl, nullptr, nullptr, N, YZ);
    k_aggr_ln<<<gN16, 256, 0, stream>>>(YZ, offs, csr, ln3_g, ln3_b, N, h3);

    // fused tail: lin1 + LN + ReLU + output projection (fp32 out)
    k_tail<<<g128, 256, 0, stream>>>(h3, wt4, l1_b, ln4_g, ln4_b, wt5, lo_b, N, out);
}

// Round 19
// 358.101 us; speedup vs baseline: 1.0044x; 1.0044x over previous
//
#include <hip/hip_runtime.h>
#include <stdint.h>

#define DEV __device__ __forceinline__

typedef __attribute__((ext_vector_type(8))) short bf16x8;   // 8 bf16 = 4 VGPRs
typedef __attribute__((ext_vector_type(4))) float f32x4;

// ---------- bf16 bit helpers ----------
DEV float bf2f(uint16_t u) { return __uint_as_float(((uint32_t)u) << 16); }
DEV uint16_t f2bfbits(float f) {          // round-to-nearest-even
    uint32_t x = __float_as_uint(f);
    uint32_t r = x + 0x7fffu + ((x >> 16) & 1u);
    return (uint16_t)(r >> 16);
}
DEV void stv(uint16_t* p, float v) { *p = f2bfbits(v); }
DEV void stv(float* p, float v) { *p = v; }

template<int C> DEV void ldbf(const uint16_t* p, float* f);
template<> DEV void ldbf<8>(const uint16_t* p, float* f) {
    uint4 v = *reinterpret_cast<const uint4*>(p);
    f[0] = __uint_as_float(v.x << 16); f[1] = __uint_as_float(v.x & 0xffff0000u);
    f[2] = __uint_as_float(v.y << 16); f[3] = __uint_as_float(v.y & 0xffff0000u);
    f[4] = __uint_as_float(v.z << 16); f[5] = __uint_as_float(v.z & 0xffff0000u);
    f[6] = __uint_as_float(v.w << 16); f[7] = __uint_as_float(v.w & 0xffff0000u);
}

// async global->LDS, 16B per lane; LDS dest = wave-uniform base + lane*16
DEV void gl16(const uint16_t* g, uint8_t* l) {
    __builtin_amdgcn_global_load_lds(
        (const __attribute__((address_space(1))) uint32_t*)g,
        (__attribute__((address_space(3))) uint32_t*)l, 16, 0, 0);
}

// counted vmcnt wait (compile-time literal; lgkm/exp untouched)
template<int N> DEV void vwait() {
    if constexpr (N == 0)      asm volatile("s_waitcnt vmcnt(0)" ::: "memory");
    else if constexpr (N == 3) asm volatile("s_waitcnt vmcnt(3)" ::: "memory");
    else if constexpr (N == 4) asm volatile("s_waitcnt vmcnt(4)" ::: "memory");
    else if constexpr (N == 6) asm volatile("s_waitcnt vmcnt(6)" ::: "memory");
    else                       asm volatile("s_waitcnt vmcnt(0)" ::: "memory");
}

// ---------------------- CSR build ----------------------
__global__ void k_count(const int* __restrict__ dst, int e, int* __restrict__ deg) {
    int i = blockIdx.x * 256 + threadIdx.x;
    if (i < e) atomicAdd(&deg[dst[i]], 1);
}

__global__ void k_block_sums(const int* __restrict__ deg, int n, int* __restrict__ bsum) {
    __shared__ int sm[256];
    int base = blockIdx.x * 1024;
    int s = 0;
    for (int i = threadIdx.x; i < 1024; i += 256) {
        int g = base + i;
        if (g < n) s += deg[g];
    }
    sm[threadIdx.x] = s; __syncthreads();
    for (int o = 128; o > 0; o >>= 1) {
        if (threadIdx.x < o) sm[threadIdx.x] += sm[threadIdx.x + o];
        __syncthreads();
    }
    if (threadIdx.x == 0) bsum[blockIdx.x] = sm[0];
}

__global__ void k_scan_bsums(int* bsum, int nb) {
    __shared__ int sm[256];
    int t = threadIdx.x;
    int v = (t < nb) ? bsum[t] : 0;
    sm[t] = v; __syncthreads();
    for (int o = 1; o < 256; o <<= 1) {
        int add = (t >= o) ? sm[t - o] : 0;
        __syncthreads();
        sm[t] += add;
        __syncthreads();
    }
    if (t < nb) bsum[t] = (t == 0) ? 0 : sm[t - 1];
}

__global__ void k_scan_final(const int* __restrict__ deg, int n,
                             const int* __restrict__ bsum, int* __restrict__ offs,
                             int* __restrict__ cursor) {
    __shared__ int sm[256];
    int t = threadIdx.x;
    int i0 = blockIdx.x * 1024 + t * 4;
    int d0 = (i0     < n) ? deg[i0]     : 0;
    int d1 = (i0 + 1 < n) ? deg[i0 + 1] : 0;
    int d2 = (i0 + 2 < n) ? deg[i0 + 2] : 0;
    int d3 = (i0 + 3 < n) ? deg[i0 + 3] : 0;
    int ts = d0 + d1 + d2 + d3;
    sm[t] = ts; __syncthreads();
    for (int o = 1; o < 256; o <<= 1) {
        int add = (t >= o) ? sm[t - o] : 0;
        __syncthreads();
        sm[t] += add;
        __syncthreads();
    }
    int e0 = bsum[blockIdx.x] + ((t == 0) ? 0 : sm[t - 1]);
    int e1 = e0 + d0, e2 = e1 + d1, e3 = e2 + d2, e4 = e3 + d3;
    if (i0     < n) { offs[i0]     = e0; cursor[i0]     = e0; }
    if (i0 + 1 < n) { offs[i0 + 1] = e1; cursor[i0 + 1] = e1; }
    if (i0 + 2 < n) { offs[i0 + 2] = e2; cursor[i0 + 2] = e2; }
    if (i0 + 3 < n) { offs[i0 + 3] = e3; cursor[i0 + 3] = e3; }
    if (i0 <= n - 1 && n - 1 < i0 + 4) offs[n] = e4;  // total
}

__global__ void k_scatter(const int* __restrict__ src, const int* __restrict__ dst, int e,
                          int* __restrict__ cursor, int* __restrict__ csr) {
    int i = blockIdx.x * 256 + threadIdx.x;
    if (i < e) {
        int p = atomicAdd(&cursor[dst[i]], 1);
        csr[p] = src[i];
    }
}

// ---------------------- fp32 -> bf16 convert ----------------------
__global__ void k_f2b(const float* __restrict__ in, uint16_t* __restrict__ o, int n4) {
    int i = blockIdx.x * 256 + threadIdx.x;
    if (i < n4) {
        float4 v = reinterpret_cast<const float4*>(in)[i];
        uint2 w;
        w.x = f2bfbits(v.x) | ((uint32_t)f2bfbits(v.y) << 16);
        w.y = f2bfbits(v.z) | ((uint32_t)f2bfbits(v.w) << 16);
        reinterpret_cast<uint2*>(o)[i] = w;
    }
}

// ---------------------- fused weight prep -> PACKED layout ----------------------
// packed[p][c][j] = W^T[c][p*8+j]  (p = k-plane = k/8, c = output col, j = k%8)
struct PrepSeg { const float* W; uint16_t* wt; int K, Dreal, ncols, koff, noff, Dtot, start, end; };
struct PrepAll { PrepSeg s[8]; };

__global__ void k_prep_all(PrepAll P, int total) {
    int idx = blockIdx.x * 256 + threadIdx.x;
    if (idx >= total) return;
#pragma unroll
    for (int i = 0; i < 8; ++i) {
        if (idx >= P.s[i].start && idx < P.s[i].end) {
            int loc = idx - P.s[i].start;
            int K = P.s[i].K;
            int nn = loc / K, k = loc - nn * K;
            float v = (nn < P.s[i].Dreal) ? P.s[i].W[(size_t)k * P.s[i].Dreal + nn] : 0.f;
            int c = P.s[i].noff + nn;
            int kk = P.s[i].koff + k;
            P.s[i].wt[((size_t)(kk >> 3) * P.s[i].Dtot + c) * 8 + (kk & 7)] = f2bfbits(v);
        }
    }
}

// ---------------------- max-aggregation, D=128: 4 nodes/wave, 16B/lane gathers ----------------------
__global__ __launch_bounds__(256) void k_aggr_max(const uint16_t* __restrict__ X,
                                                  const int* __restrict__ offs,
                                                  const int* __restrict__ csr,
                                                  int n, uint16_t* __restrict__ out) {
    int sl = threadIdx.x & 15;
    int node = blockIdx.x * 16 + (threadIdx.x >> 4);
    if (node >= n) return;
    int beg = offs[node], end = offs[node + 1];
    float acc[8] = {};
    const size_t loff = (size_t)sl * 8;
    int i = beg;
    for (; i + 3 < end; i += 4) {
        int s0 = csr[i], s1 = csr[i + 1], s2 = csr[i + 2], s3 = csr[i + 3];
        float f0[8], f1[8], f2[8], f3[8];
        ldbf<8>(X + (size_t)s0 * 128 + loff, f0);
        ldbf<8>(X + (size_t)s1 * 128 + loff, f1);
        ldbf<8>(X + (size_t)s2 * 128 + loff, f2);
        ldbf<8>(X + (size_t)s3 * 128 + loff, f3);
#pragma unroll
        for (int c = 0; c < 8; c++)
            acc[c] = fmaxf(acc[c], fmaxf(fmaxf(f0[c], f1[c]), fmaxf(f2[c], f3[c])));
    }
    for (; i < end; ++i) {
        int s = csr[i];
        float f[8];
        ldbf<8>(X + (size_t)s * 128 + loff, f);
#pragma unroll
        for (int c = 0; c < 8; c++) acc[c] = fmaxf(acc[c], f[c]);
    }
    uint4 v;
    v.x = f2bfbits(acc[0]) | ((uint32_t)f2bfbits(acc[1]) << 16);
    v.y = f2bfbits(acc[2]) | ((uint32_t)f2bfbits(acc[3]) << 16);
    v.z = f2bfbits(acc[4]) | ((uint32_t)f2bfbits(acc[5]) << 16);
    v.w = f2bfbits(acc[6]) | ((uint32_t)f2bfbits(acc[7]) << 16);
    *reinterpret_cast<uint4*>(out + (size_t)node * 128 + loff) = v;
}

// ---------------------- mean-aggregate(Y) + Z + LN + ReLU, 4 nodes/wave, 16B/lane ----------------------
__global__ __launch_bounds__(256) void k_aggr_ln(const uint16_t* __restrict__ YZ,
                                                 const int* __restrict__ offs,
                                                 const int* __restrict__ csr,
                                                 const float* __restrict__ g,
                                                 const float* __restrict__ b,
                                                 int n, uint16_t* __restrict__ out) {
    int sl = threadIdx.x & 15;
    int node = blockIdx.x * 16 + (threadIdx.x >> 4);
    if (node >= n) return;
    int beg = offs[node], end = offs[node + 1];
    float a[8] = {};
    const size_t loff = (size_t)sl * 8;
    int i = beg;
    for (; i + 3 < end; i += 4) {
        int s0 = csr[i], s1 = csr[i + 1], s2 = csr[i + 2], s3 = csr[i + 3];
        float f0[8], f1[8], f2[8], f3[8];
        ldbf<8>(YZ + (size_t)s0 * 256 + loff, f0);
        ldbf<8>(YZ + (size_t)s1 * 256 + loff, f1);
        ldbf<8>(YZ + (size_t)s2 * 256 + loff, f2);
        ldbf<8>(YZ + (size_t)s3 * 256 + loff, f3);
#pragma unroll
        for (int c = 0; c < 8; c++) a[c] += (f0[c] + f1[c]) + (f2[c] + f3[c]);
    }
    for (; i < end; ++i) {
        int s = csr[i];
        float f[8];
        ldbf<8>(YZ + (size_t)s * 256 + loff, f);
#pragma unroll
        for (int c = 0; c < 8; c++) a[c] += f[c];
    }
    int d = end - beg; if (d < 1) d = 1;
    float scale = 1.f / (float)d;
    float z[8];
    ldbf<8>(YZ + (size_t)node * 256 + 128 + loff, z);
    float v[8];
#pragma unroll
    for (int c = 0; c < 8; c++) v[c] = a[c] * scale + z[c];
    float s = 0.f, s2 = 0.f;
#pragma unroll
    for (int c = 0; c < 8; c++) { s += v[c]; s2 += v[c] * v[c]; }
#pragma unroll
    for (int o = 1; o < 16; o <<= 1) { s += __shfl_xor(s, o); s2 += __shfl_xor(s2, o); }
    float mean = s * (1.f / 128.f);
    float var = s2 * (1.f / 128.f) - mean * mean;
    float inv = rsqrtf(var + 1e-5f);
    float y[8];
#pragma unroll
    for (int c = 0; c < 8; c++)
        y[c] = fmaxf((v[c] - mean) * inv * g[loff + c] + b[loff + c], 0.f);
    uint4 w;
    w.x = f2bfbits(y[0]) | ((uint32_t)f2bfbits(y[1]) << 16);
    w.y = f2bfbits(y[2]) | ((uint32_t)f2bfbits(y[3]) << 16);
    w.z = f2bfbits(y[4]) | ((uint32_t)f2bfbits(y[5]) << 16);
    w.w = f2bfbits(y[6]) | ((uint32_t)f2bfbits(y[7]) << 16);
    *reinterpret_cast<uint4*>(out + (size_t)node * 128 + loff) = w;
}

// ---------------------- MFMA GEMM (R17): R10 pipeline + packed-W contiguous staging ----------------------
// block = 128 rows x DB cols; 4 waves, wave = 32 rows x DB cols. Used for layers 1 and 2.
template<int KPER, int DOUT, int DB, bool DUAL, bool LN, bool ZBIAS, typename TO>
__global__ __launch_bounds__(256) void k_mf(const uint16_t* __restrict__ A0,
                                            const uint16_t* __restrict__ A1,
                                            const uint16_t* __restrict__ WT,
                                            const float* __restrict__ bias,
                                            const float* __restrict__ g,
                                            const float* __restrict__ bvec,
                                            int n, TO* __restrict__ out) {
    constexpr int KEFF = KPER * (DUAL ? 2 : 1);
    constexpr int NST = KEFF / 32;        // k-steps
    constexpr int NF = DB / 16;
    constexpr int WPL = DB * 16;          // W plane bytes per 8-k chunk
    constexpr int AB = 8192;              // A tile bytes (128 rows x 32 k x 2B)
    constexpr int WB = DB * 64;           // W tile bytes (DB cols x 32 k x 2B)
    constexpr int HB = DB / 64;           // W 1KB-chunks per wave (1,2,4)
    constexpr int L  = 2 + HB;            // gl16 per wave per stage
    __shared__ __align__(16) uint8_t lds[3][AB + WB];

    int tid = threadIdx.x;
    int lane = tid & 63, wid = tid >> 6;
    int lr = lane & 15, kb = lane >> 4;
    int row0 = blockIdx.x * 128;
    int wrow = wid * 32;

    auto stage = [&](int kt, uint8_t* buf) {
        const uint16_t* Asel = A0; int kk = kt;
        if (DUAL && kt >= KPER) { Asel = A1; kk = kt - KPER; }
        uint8_t* aB = buf;
        uint8_t* wB = buf + AB;
#pragma unroll
        for (int j = 0; j < 2; ++j) {
            int p = wid * 2 + j, cb = p >> 1, h = p & 1;
            int grow = row0 + h * 64 + lane; if (grow >= n) grow = n - 1;
            gl16(Asel + (size_t)grow * KPER + kk + cb * 8, aB + cb * 2048 + h * 1024);
        }
#pragma unroll
        for (int j = 0; j < HB; ++j) {
            int p = wid * HB + j, cb = p / HB, h = p % HB;
            int plane = (kt >> 3) + cb;
            gl16(WT + ((size_t)plane * DB + h * 64 + lane) * 8, wB + cb * WPL + h * 1024);
        }
    };

    f32x4 acc[2][NF] = {};
    stage(0, lds[0]);
    if constexpr (NST > 1) stage(32, lds[1]);

#pragma unroll
    for (int s = 0; s < NST; ++s) {
        if (s < NST - 1) vwait<L>(); else vwait<0>();   // own stage-s loads landed
        __builtin_amdgcn_s_barrier();                    // all waves' stage-s loads landed
        __builtin_amdgcn_sched_barrier(0);               // nothing crosses upward
        if (s + 2 < NST) stage((s + 2) * 32, lds[(s + 2) % 3]);
        const uint8_t* aB = lds[s % 3];
        const uint8_t* wB = lds[s % 3] + AB;
        bf16x8 af0 = *reinterpret_cast<const bf16x8*>(aB + kb * 2048 + (wrow + lr) * 16);
        bf16x8 af1 = *reinterpret_cast<const bf16x8*>(aB + kb * 2048 + (wrow + 16 + lr) * 16);
#pragma unroll
        for (int nf = 0; nf < NF; ++nf) {
            bf16x8 wf = *reinterpret_cast<const bf16x8*>(wB + kb * WPL + (nf * 16 + lr) * 16);
            acc[0][nf] = __builtin_amdgcn_mfma_f32_16x16x32_bf16(af0, wf, acc[0][nf], 0, 0, 0);
            acc[1][nf] = __builtin_amdgcn_mfma_f32_16x16x32_bf16(af1, wf, acc[1][nf], 0, 0, 0);
        }
    }

    // ---- epilogue: bias (+ LN + ReLU), store ----
#pragma unroll
    for (int nf = 0; nf < NF; ++nf) {
        int col = nf * 16 + lr;
        float bsv;
        if constexpr (ZBIAS) {
            bsv = (col >= DOUT / 2) ? bias[col - DOUT / 2] : 0.f;
        } else {
            bsv = (DB == DOUT || col < DOUT) ? bias[col] : 0.f;
        }
#pragma unroll
        for (int r = 0; r < 4; ++r) { acc[0][nf][r] += bsv; acc[1][nf][r] += bsv; }
    }
    if constexpr (LN) {
        float gv[NF], bv2[NF];
#pragma unroll
        for (int nf = 0; nf < NF; ++nf) {
            int col = nf * 16 + lr;
            gv[nf] = g[col]; bv2[nf] = bvec[col];
        }
#pragma unroll
        for (int m = 0; m < 2; ++m) {
            float s[4], s2[4];
#pragma unroll
            for (int r = 0; r < 4; ++r) { s[r] = 0.f; s2[r] = 0.f; }
#pragma unroll
            for (int nf = 0; nf < NF; ++nf)
#pragma unroll
                for (int r = 0; r < 4; ++r) { float v = acc[m][nf][r]; s[r] += v; s2[r] += v * v; }
#pragma unroll
            for (int r = 0; r < 4; ++r) {
#pragma unroll
                for (int o = 1; o < 16; o <<= 1) {
                    s[r] += __shfl_xor(s[r], o);
                    s2[r] += __shfl_xor(s2[r], o);
                }
                float mean = s[r] / DOUT;
                float var = s2[r] / DOUT - mean * mean;
                float inv = rsqrtf(var + 1e-5f);
#pragma unroll
                for (int nf = 0; nf < NF; ++nf) {
                    float y = (acc[m][nf][r] - mean) * inv * gv[nf] + bv2[nf];
                    acc[m][nf][r] = fmaxf(y, 0.f);
                }
            }
        }
    }
#pragma unroll
    for (int m = 0; m < 2; ++m)
#pragma unroll
        for (int r = 0; r < 4; ++r) {
            int row = row0 + wrow + m * 16 + kb * 4 + r;
            if (row < n) {
#pragma unroll
                for (int nf = 0; nf < NF; ++nf) {
                    int col = nf * 16 + lr;
                    if (DB == DOUT || col < DOUT)
                        stv(out + (size_t)row * DOUT + col, acc[m][nf][r]);
                }
            }
        }
}

// ---------------------- MFMA GEMM (R18 panel variant): layer 3 only ----------------------
// block = 64 rows x 256 cols; 4 waves of 16 rows. A panel (whole rows, contiguous 1KB gl16,
// rule-#21 XOR swizzle); W packed, triple-buffered, counted vmcnt.
template<int KPER, int DOUT, bool ZBIAS>
__global__ __launch_bounds__(256) void k_mfp(const uint16_t* __restrict__ A0,
                                             const uint16_t* __restrict__ WT,
                                             const float* __restrict__ bias,
                                             int n, uint16_t* __restrict__ out) {
    constexpr int DB = 256;
    constexpr int NST = KPER / 32;
    constexpr int NF = DB / 16;
    constexpr int WPL = DB * 16;
    constexpr int WB = DB * 64;
    constexpr int HB = DB / 64;
    constexpr int RB = KPER * 2;          // A row bytes
    constexpr int PAN = 64 * RB;
    constexpr int PCH = PAN / 1024;
    __shared__ __align__(16) uint8_t aP[PAN];
    __shared__ __align__(16) uint8_t wL[3][WB];

    int tid = threadIdx.x;
    int lane = tid & 63, wid = tid >> 6;
    int lr = lane & 15, kb = lane >> 4;
    int row0 = blockIdx.x * 64;

    for (int c = wid; c < PCH; c += 4) {
        int rloc, colb;
        if constexpr (RB == 256) { rloc = c * 4 + (lane >> 4); colb = (lane & 15) * 16; }
        else                     { rloc = c * 2 + (lane >> 5); colb = (lane & 31) * 16; }
        int grow = row0 + rloc; if (grow >= n) grow = n - 1;
        gl16((const uint16_t*)((const uint8_t*)A0 + (size_t)grow * RB + (colb ^ ((rloc & 7) << 4))),
             aP + (size_t)c * 1024);
    }

    auto stageW = [&](int kt, uint8_t* buf) {
#pragma unroll
        for (int j = 0; j < HB; ++j) {
            int p = wid * HB + j, cb = p / HB, h = p % HB;
            int plane = (kt >> 3) + cb;
            gl16(WT + ((size_t)plane * DB + h * 64 + lane) * 8, buf + cb * WPL + h * 1024);
        }
    };

    stageW(0, wL[0]);
    if constexpr (NST > 1) stageW(32, wL[1]);
    vwait<0>();
    __builtin_amdgcn_s_barrier();
    __builtin_amdgcn_sched_barrier(0);

    f32x4 acc[NF] = {};
#pragma unroll
    for (int s = 0; s < NST; ++s) {
        if (s > 0) {
            if (s < NST - 1) vwait<4>(); else vwait<0>();
            __builtin_amdgcn_s_barrier();
            __builtin_amdgcn_sched_barrier(0);
        }
        if (s + 2 < NST) stageW((s + 2) * 32, wL[(s + 2) % 3]);
        int kk = s * 32;
        int ar = wid * 16 + lr;
        bf16x8 af = *reinterpret_cast<const bf16x8*>(
            aP + (size_t)ar * RB + (((kk + kb * 8) * 2) ^ ((ar & 7) << 4)));
        const uint8_t* wB = wL[s % 3];
#pragma unroll
        for (int nf = 0; nf < NF; ++nf) {
            bf16x8 wf = *reinterpret_cast<const bf16x8*>(wB + kb * WPL + (nf * 16 + lr) * 16);
            acc[nf] = __builtin_amdgcn_mfma_f32_16x16x32_bf16(af, wf, acc[nf], 0, 0, 0);
        }
    }

#pragma unroll
    for (int nf = 0; nf < NF; ++nf) {
        int col = nf * 16 + lr;
        float bsv;
        if constexpr (ZBIAS) {
            bsv = (col >= DOUT / 2) ? bias[col - DOUT / 2] : 0.f;
        } else {
            bsv = (col < DOUT) ? bias[col] : 0.f;
        }
#pragma unroll
        for (int r = 0; r < 4; ++r) acc[nf][r] += bsv;
    }
#pragma unroll
    for (int r = 0; r < 4; ++r) {
        int row = row0 + wid * 16 + kb * 4 + r;
        if (row < n) {
#pragma unroll
            for (int nf = 0; nf < NF; ++nf) {
                int col = nf * 16 + lr;
                if (col < DOUT)
                    stv(out + (size_t)row * DOUT + col, acc[nf][r]);
            }
        }
    }
}

// ---------------------- fused tail: h4 = LN(relu(h3@W4+b4)); out = h4@W5 + b5 ----------------------
__global__ __launch_bounds__(256) void k_tail(const uint16_t* __restrict__ A,
                                              const uint16_t* __restrict__ WT4,
                                              const float* __restrict__ b4,
                                              const float* __restrict__ g4,
                                              const float* __restrict__ bv4,
                                              const uint16_t* __restrict__ WT5,
                                              const float* __restrict__ b5,
                                              int n, float* __restrict__ out) {
    __shared__ __align__(16) uint8_t lds[3][8192 + 4096];
    __shared__ __align__(16) uint8_t w5L[16384];
    __shared__ __align__(16) uint8_t h4L[16384];

    int tid = threadIdx.x;
    int lane = tid & 63, wid = tid >> 6;
    int lr = lane & 15, kb = lane >> 4;
    int row0 = blockIdx.x * 128;
    int wrow = wid * 32;

    auto stage = [&](int kt, uint8_t* buf) {
        uint8_t* aB = buf;
        uint8_t* wB = buf + 8192;
#pragma unroll
        for (int j = 0; j < 2; ++j) {
            int p = wid * 2 + j, cb = p >> 1, h = p & 1;
            int grow = row0 + h * 64 + lane; if (grow >= n) grow = n - 1;
            gl16(A + (size_t)grow * 128 + kt + cb * 8, aB + cb * 2048 + h * 1024);
        }
        gl16(WT4 + ((size_t)((kt >> 3) + wid) * 64 + lane) * 8, wB + wid * 1024);
    };

#pragma unroll
    for (int j = 0; j < 4; ++j) {
        int p = wid * 4 + j, cb = p >> 1, h = p & 1;
        gl16(WT5 + ((size_t)cb * 128 + h * 64 + lane) * 8, w5L + cb * 2048 + h * 1024);
    }

    f32x4 acc1[2][4] = {};
    stage(0, lds[0]);
    stage(32, lds[1]);

#pragma unroll
    for (int s = 0; s < 4; ++s) {
        if (s < 3) vwait<3>(); else vwait<0>();
        __builtin_amdgcn_s_barrier();
        __builtin_amdgcn_sched_barrier(0);
        if (s + 2 < 4) stage((s + 2) * 32, lds[(s + 2) % 3]);
        const uint8_t* aB = lds[s % 3];
        const uint8_t* wB = lds[s % 3] + 8192;
        bf16x8 af0 = *reinterpret_cast<const bf16x8*>(aB + kb * 2048 + (wrow + lr) * 16);
        bf16x8 af1 = *reinterpret_cast<const bf16x8*>(aB + kb * 2048 + (wrow + 16 + lr) * 16);
#pragma unroll
        for (int nf = 0; nf < 4; ++nf) {
            bf16x8 wf = *reinterpret_cast<const bf16x8*>(wB + kb * 1024 + (nf * 16 + lr) * 16);
            acc1[0][nf] = __builtin_amdgcn_mfma_f32_16x16x32_bf16(af0, wf, acc1[0][nf], 0, 0, 0);
            acc1[1][nf] = __builtin_amdgcn_mfma_f32_16x16x32_bf16(af1, wf, acc1[1][nf], 0, 0, 0);
        }
    }

#pragma unroll
    for (int nf = 0; nf < 4; ++nf) {
        float bsv = b4[nf * 16 + lr];
#pragma unroll
        for (int r = 0; r < 4; ++r) { acc1[0][nf][r] += bsv; acc1[1][nf][r] += bsv; }
    }
    {
        float gv[4], bv2[4];
#pragma unroll
        for (int nf = 0; nf < 4; ++nf) { gv[nf] = g4[nf * 16 + lr]; bv2[nf] = bv4[nf * 16 + lr]; }
#pragma unroll
        for (int m = 0; m < 2; ++m) {
            float s[4] = {}, s2[4] = {};
#pragma unroll
            for (int nf = 0; nf < 4; ++nf)
#pragma unroll
                for (int r = 0; r < 4; ++r) { float v = acc1[m][nf][r]; s[r] += v; s2[r] += v * v; }
#pragma unroll
            for (int r = 0; r < 4; ++r) {
#pragma unroll
                for (int o = 1; o < 16; o <<= 1) { s[r] += __shfl_xor(s[r], o); s2[r] += __shfl_xor(s2[r], o); }
                float mean = s[r] * (1.f / 64.f);
                float var = s2[r] * (1.f / 64.f) - mean * mean;
                float inv = rsqrtf(var + 1e-5f);
#pragma unroll
                for (int nf = 0; nf < 4; ++nf)
                    acc1[m][nf][r] = fmaxf((acc1[m][nf][r] - mean) * inv * gv[nf] + bv2[nf], 0.f);
            }
        }
    }

#pragma unroll
    for (int m = 0; m < 2; ++m)
#pragma unroll
        for (int r = 0; r < 4; ++r) {
            int row = wrow + m * 16 + kb * 4 + r;
#pragma unroll
            for (int nf = 0; nf < 4; ++nf) {
                int col = nf * 16 + lr;
                *reinterpret_cast<uint16_t*>(h4L + ((col >> 3) * 2048 + row * 16 + (col & 7) * 2)) =
                    f2bfbits(acc1[m][nf][r]);
            }
        }
    __syncthreads();

    f32x4 acc2[2][8] = {};
#pragma unroll
    for (int s = 0; s < 2; ++s) {
        bf16x8 af0 = *reinterpret_cast<const bf16x8*>(h4L + (s * 4 + kb) * 2048 + (wrow + lr) * 16);
        bf16x8 af1 = *reinterpret_cast<const bf16x8*>(h4L + (s * 4 + kb) * 2048 + (wrow + 16 + lr) * 16);
#pragma unroll
        for (int nf = 0; nf < 8; ++nf) {
            bf16x8 wf = *reinterpret_cast<const bf16x8*>(w5L + (s * 4 + kb) * 2048 + (nf * 16 + lr) * 16);
            acc2[0][nf] = __builtin_amdgcn_mfma_f32_16x16x32_bf16(af0, wf, acc2[0][nf], 0, 0, 0);
            acc2[1][nf] = __builtin_amdgcn_mfma_f32_16x16x32_bf16(af1, wf, acc2[1][nf], 0, 0, 0);
        }
    }
#pragma unroll
    for (int m = 0; m < 2; ++m)
#pragma unroll
        for (int r = 0; r < 4; ++r) {
            int row = row0 + wrow + m * 16 + kb * 4 + r;
            if (row < n) {
#pragma unroll
                for (int nf = 0; nf < 8; ++nf) {
                    int col = nf * 16 + lr;
                    if (col < 100)
                        out[(size_t)row * 100 + col] = acc2[m][nf][r] + b5[col];
                }
            }
        }
}

// ---------------------- launcher ----------------------
extern "C" void kernel_launch(void* const* d_in, const int* in_sizes, int n_in,
                              void* d_out, int out_size, void* d_ws, size_t ws_size,
                              hipStream_t stream) {
    const float* x     = (const float*)d_in[0];
    const int*   src   = (const int*)d_in[1];
    const int*   dst   = (const int*)d_in[2];
    const float* s1_wl = (const float*)d_in[3];
    const float* s1_bl = (const float*)d_in[4];
    const float* s1_wr = (const float*)d_in[5];
    const float* ln1_g = (const float*)d_in[6];
    const float* ln1_b = (const float*)d_in[7];
    const float* s2_wl = (const float*)d_in[8];
    const float* s2_bl = (const float*)d_in[9];
    const float* s2_wr = (const float*)d_in[10];
    const float* ln2_g = (const float*)d_in[11];
    const float* ln2_b = (const float*)d_in[12];
    const float* s3_wl = (const float*)d_in[13];
    const float* s3_bl = (const float*)d_in[14];
    const float* s3_wr = (const float*)d_in[15];
    const float* ln3_g = (const float*)d_in[16];
    const float* ln3_b = (const float*)d_in[17];
    const float* l1_w  = (const float*)d_in[18];
    const float* l1_b  = (const float*)d_in[19];
    const float* ln4_g = (const float*)d_in[20];
    const float* ln4_b = (const float*)d_in[21];
    const float* lo_w  = (const float*)d_in[22];
    const float* lo_b  = (const float*)d_in[23];
    float* out = (float*)d_out;

    const int N = in_sizes[0] / 128;
    const int E = in_sizes[1];
    (void)n_in; (void)out_size; (void)ws_size;

    char* w = (char*)d_ws;
    size_t off = 0;
    auto alloc = [&](size_t bytes) -> void* {
        void* p = w + off;
        off = (off + bytes + 255) & ~(size_t)255;
        return p;
    };
    int* deg    = (int*)alloc((size_t)N * 4);
    int* offs   = (int*)alloc((size_t)(N + 1) * 4);
    int* cursor = (int*)alloc((size_t)N * 4);
    int* bsum   = (int*)alloc(1024 * 4);
    int* csr    = (int*)alloc((size_t)E * 4);
    uint16_t* wt1 = (uint16_t*)alloc(256 * 128 * 2);   // packed [16 planes][256 cols][8]
    uint16_t* wt2 = (uint16_t*)alloc(256 * 256 * 2);   // packed [32 planes][256 cols][8]
    uint16_t* wt3 = (uint16_t*)alloc(256 * 256 * 2);   // packed [32 planes][256 cols][8]
    uint16_t* wt4 = (uint16_t*)alloc(64 * 128 * 2);    // packed [16 planes][64 cols][8]
    uint16_t* wt5 = (uint16_t*)alloc(128 * 64 * 2);    // packed [8 planes][128 cols][8]
    uint16_t* xb    = (uint16_t*)alloc((size_t)N * 128 * 2);
    uint16_t* YZ    = (uint16_t*)alloc((size_t)N * 256 * 2);  // [Y|Z] for layers 1 and 3
    uint16_t* h1    = (uint16_t*)alloc((size_t)N * 128 * 2);
    uint16_t* aggrB = (uint16_t*)alloc((size_t)N * 128 * 2);  // max-aggr output
    uint16_t* h2    = (uint16_t*)alloc((size_t)N * 256 * 2);
    uint16_t* h3    = (uint16_t*)alloc((size_t)N * 128 * 2);

    int gE = (E + 255) / 256;
    int nb = (N + 1023) / 1024;
    int gN16 = (N + 15) / 16;
    int g64  = (N + 63) / 64;
    int g128 = (N + 127) / 128;

    // CSR build
    hipMemsetAsync(deg, 0, (size_t)N * 4, stream);
    k_count<<<gE, 256, 0, stream>>>(dst, E, deg);
    k_block_sums<<<nb, 256, 0, stream>>>(deg, N, bsum);
    k_scan_bsums<<<1, 256, 0, stream>>>(bsum, nb);
    k_scan_final<<<nb, 256, 0, stream>>>(deg, N, bsum, offs, cursor);
    k_scatter<<<gE, 256, 0, stream>>>(src, dst, E, cursor, csr);

    // fused weight prep (packed layout)
    PrepAll P;
    int cum = 0;
    auto seg = [&](int i, const float* W, uint16_t* wt, int K, int Dreal, int ncols,
                   int koff, int noff, int Dtot) {
        P.s[i] = {W, wt, K, Dreal, ncols, koff, noff, Dtot, cum, cum + ncols * K};
        cum += ncols * K;
    };
    seg(0, s1_wl, wt1, 128, 128, 128, 0,   0,   256);
    seg(1, s1_wr, wt1, 128, 128, 128, 0,   128, 256);
    seg(2, s2_wl, wt2, 128, 256, 256, 0,   0,   256);
    seg(3, s2_wr, wt2, 128, 256, 256, 128, 0,   256);
    seg(4, s3_wl, wt3, 256, 128, 128, 0,   0,   256);
    seg(5, s3_wr, wt3, 256, 128, 128, 0,   128, 256);
    seg(6, l1_w,  wt4, 128, 64,  64,  0,   0,   64);
    seg(7, lo_w,  wt5, 64,  100, 128, 0,   0,   128);
    k_prep_all<<<(cum + 255) / 256, 256, 0, stream>>>(P, cum);

    // x -> bf16
    k_f2b<<<(N * 128 / 4 + 255) / 256, 256, 0, stream>>>(x, xb, N * 128 / 4);

    // layer 1 (mean, reordered): YZ1 = xb @ [Wl1|Wr1] (+bl on Z half); h1 = LN(mean(Y1)+Z1)
    k_mf<128, 256, 256, false, false, true, uint16_t><<<g128, 256, 0, stream>>>(
        xb, nullptr, wt1, s1_bl, nullptr, nullptr, N, YZ);
    k_aggr_ln<<<gN16, 256, 0, stream>>>(YZ, offs, csr, ln1_g, ln1_b, N, h1);

    // layer 2 (max): aggrB = max-gather(h1); h2 = LN([aggrB|h1] @ wt2 + b2)
    k_aggr_max<<<gN16, 256, 0, stream>>>(h1, offs, csr, N, aggrB);
    k_mf<128, 256, 256, true, true, false, uint16_t><<<g128, 256, 0, stream>>>(
        aggrB, h1, wt2, s2_bl, ln2_g, ln2_b, N, h2);

    // layer 3 (mean, reordered, A-panel variant): YZ3 = h2 @ [Wl3|Wr3]; h3 = LN(mean(Y3)+Z3)
    k_mfp<256, 256, true><<<g64, 256, 0, stream>>>(h2, wt3, s3_bl, N, YZ);
    k_aggr_ln<<<gN16, 256, 0, stream>>>(YZ, offs, csr, ln3_g, ln3_b, N, h3);

    // fused tail: lin1 + LN + ReLU + output projection (fp32 out)
    k_tail<<<g128, 256, 0, stream>>>(h3, wt4, l1_b, ln4_g, ln4_b, wt5, lo_b, N, out);
}

// Round 20
// 346.594 us; speedup vs baseline: 1.0377x; 1.0332x over previous
//
#include <hip/hip_runtime.h>
#include <stdint.h>

#define DEV __device__ __forceinline__

typedef __attribute__((ext_vector_type(8))) short bf16x8;   // 8 bf16 = 4 VGPRs
typedef __attribute__((ext_vector_type(4))) float f32x4;

// ---------- bf16 bit helpers ----------
DEV float bf2f(uint16_t u) { return __uint_as_float(((uint32_t)u) << 16); }
DEV uint16_t f2bfbits(float f) {          // round-to-nearest-even
    uint32_t x = __float_as_uint(f);
    uint32_t r = x + 0x7fffu + ((x >> 16) & 1u);
    return (uint16_t)(r >> 16);
}
DEV void stv(uint16_t* p, float v) { *p = f2bfbits(v); }
DEV void stv(float* p, float v) { *p = v; }

template<int C> DEV void ldbf(const uint16_t* p, float* f);
template<> DEV void ldbf<8>(const uint16_t* p, float* f) {
    uint4 v = *reinterpret_cast<const uint4*>(p);
    f[0] = __uint_as_float(v.x << 16); f[1] = __uint_as_float(v.x & 0xffff0000u);
    f[2] = __uint_as_float(v.y << 16); f[3] = __uint_as_float(v.y & 0xffff0000u);
    f[4] = __uint_as_float(v.z << 16); f[5] = __uint_as_float(v.z & 0xffff0000u);
    f[6] = __uint_as_float(v.w << 16); f[7] = __uint_as_float(v.w & 0xffff0000u);
}

// async global->LDS, 16B per lane; LDS dest = wave-uniform base + lane*16
DEV void gl16(const uint16_t* g, uint8_t* l) {
    __builtin_amdgcn_global_load_lds(
        (const __attribute__((address_space(1))) uint32_t*)g,
        (__attribute__((address_space(3))) uint32_t*)l, 16, 0, 0);
}

// counted vmcnt wait (compile-time literal; lgkm/exp untouched)
template<int N> DEV void vwait() {
    if constexpr (N == 0)      asm volatile("s_waitcnt vmcnt(0)" ::: "memory");
    else if constexpr (N == 3) asm volatile("s_waitcnt vmcnt(3)" ::: "memory");
    else if constexpr (N == 4) asm volatile("s_waitcnt vmcnt(4)" ::: "memory");
    else if constexpr (N == 6) asm volatile("s_waitcnt vmcnt(6)" ::: "memory");
    else                       asm volatile("s_waitcnt vmcnt(0)" ::: "memory");
}

// ---------------------- CSR build ----------------------
__global__ void k_count(const int* __restrict__ dst, int e, int* __restrict__ deg) {
    int i = blockIdx.x * 256 + threadIdx.x;
    if (i < e) atomicAdd(&deg[dst[i]], 1);
}

__global__ void k_block_sums(const int* __restrict__ deg, int n, int* __restrict__ bsum) {
    __shared__ int sm[256];
    int base = blockIdx.x * 1024;
    int s = 0;
    for (int i = threadIdx.x; i < 1024; i += 256) {
        int g = base + i;
        if (g < n) s += deg[g];
    }
    sm[threadIdx.x] = s; __syncthreads();
    for (int o = 128; o > 0; o >>= 1) {
        if (threadIdx.x < o) sm[threadIdx.x] += sm[threadIdx.x + o];
        __syncthreads();
    }
    if (threadIdx.x == 0) bsum[blockIdx.x] = sm[0];
}

__global__ void k_scan_bsums(int* bsum, int nb) {
    __shared__ int sm[256];
    int t = threadIdx.x;
    int v = (t < nb) ? bsum[t] : 0;
    sm[t] = v; __syncthreads();
    for (int o = 1; o < 256; o <<= 1) {
        int add = (t >= o) ? sm[t - o] : 0;
        __syncthreads();
        sm[t] += add;
        __syncthreads();
    }
    if (t < nb) bsum[t] = (t == 0) ? 0 : sm[t - 1];
}

__global__ void k_scan_final(const int* __restrict__ deg, int n,
                             const int* __restrict__ bsum, int* __restrict__ offs,
                             int* __restrict__ cursor) {
    __shared__ int sm[256];
    int t = threadIdx.x;
    int i0 = blockIdx.x * 1024 + t * 4;
    int d0 = (i0     < n) ? deg[i0]     : 0;
    int d1 = (i0 + 1 < n) ? deg[i0 + 1] : 0;
    int d2 = (i0 + 2 < n) ? deg[i0 + 2] : 0;
    int d3 = (i0 + 3 < n) ? deg[i0 + 3] : 0;
    int ts = d0 + d1 + d2 + d3;
    sm[t] = ts; __syncthreads();
    for (int o = 1; o < 256; o <<= 1) {
        int add = (t >= o) ? sm[t - o] : 0;
        __syncthreads();
        sm[t] += add;
        __syncthreads();
    }
    int e0 = bsum[blockIdx.x] + ((t == 0) ? 0 : sm[t - 1]);
    int e1 = e0 + d0, e2 = e1 + d1, e3 = e2 + d2, e4 = e3 + d3;
    if (i0     < n) { offs[i0]     = e0; cursor[i0]     = e0; }
    if (i0 + 1 < n) { offs[i0 + 1] = e1; cursor[i0 + 1] = e1; }
    if (i0 + 2 < n) { offs[i0 + 2] = e2; cursor[i0 + 2] = e2; }
    if (i0 + 3 < n) { offs[i0 + 3] = e3; cursor[i0 + 3] = e3; }
    if (i0 <= n - 1 && n - 1 < i0 + 4) offs[n] = e4;  // total
}

__global__ void k_scatter(const int* __restrict__ src, const int* __restrict__ dst, int e,
                          int* __restrict__ cursor, int* __restrict__ csr) {
    int i = blockIdx.x * 256 + threadIdx.x;
    if (i < e) {
        int p = atomicAdd(&cursor[dst[i]], 1);
        csr[p] = src[i];
    }
}

// ---------------------- fp32 -> bf16 convert ----------------------
__global__ void k_f2b(const float* __restrict__ in, uint16_t* __restrict__ o, int n4) {
    int i = blockIdx.x * 256 + threadIdx.x;
    if (i < n4) {
        float4 v = reinterpret_cast<const float4*>(in)[i];
        uint2 w;
        w.x = f2bfbits(v.x) | ((uint32_t)f2bfbits(v.y) << 16);
        w.y = f2bfbits(v.z) | ((uint32_t)f2bfbits(v.w) << 16);
        reinterpret_cast<uint2*>(o)[i] = w;
    }
}

// ---------------------- fused weight prep -> PACKED layout ----------------------
// packed[p][c][j] = W^T[c][p*8+j]  (p = k-plane = k/8, c = output col, j = k%8)
// so a wave's gl16 over 64 consecutive c reads CONTIGUOUS 1KB.
struct PrepSeg { const float* W; uint16_t* wt; int K, Dreal, ncols, koff, noff, Dtot, start, end; };
struct PrepAll { PrepSeg s[8]; };

__global__ void k_prep_all(PrepAll P, int total) {
    int idx = blockIdx.x * 256 + threadIdx.x;
    if (idx >= total) return;
#pragma unroll
    for (int i = 0; i < 8; ++i) {
        if (idx >= P.s[i].start && idx < P.s[i].end) {
            int loc = idx - P.s[i].start;
            int K = P.s[i].K;
            int nn = loc / K, k = loc - nn * K;
            float v = (nn < P.s[i].Dreal) ? P.s[i].W[(size_t)k * P.s[i].Dreal + nn] : 0.f;
            int c = P.s[i].noff + nn;
            int kk = P.s[i].koff + k;
            P.s[i].wt[((size_t)(kk >> 3) * P.s[i].Dtot + c) * 8 + (kk & 7)] = f2bfbits(v);
        }
    }
}

// ---------------------- max-aggregation, D=128: 4 nodes/wave, 16B/lane gathers ----------------------
__global__ __launch_bounds__(256) void k_aggr_max(const uint16_t* __restrict__ X,
                                                  const int* __restrict__ offs,
                                                  const int* __restrict__ csr,
                                                  int n, uint16_t* __restrict__ out) {
    int sl = threadIdx.x & 15;                        // sub-lane within node group
    int node = blockIdx.x * 16 + (threadIdx.x >> 4);  // 16 nodes per 256-thread block
    if (node >= n) return;
    int beg = offs[node], end = offs[node + 1];
    float acc[8] = {};
    const size_t loff = (size_t)sl * 8;               // 8 bf16 = 16B per lane, 16 lanes = full row
    int i = beg;
    for (; i + 3 < end; i += 4) {                     // 4 rows in flight (16B each)
        int s0 = csr[i], s1 = csr[i + 1], s2 = csr[i + 2], s3 = csr[i + 3];
        float f0[8], f1[8], f2[8], f3[8];
        ldbf<8>(X + (size_t)s0 * 128 + loff, f0);
        ldbf<8>(X + (size_t)s1 * 128 + loff, f1);
        ldbf<8>(X + (size_t)s2 * 128 + loff, f2);
        ldbf<8>(X + (size_t)s3 * 128 + loff, f3);
#pragma unroll
        for (int c = 0; c < 8; c++)
            acc[c] = fmaxf(acc[c], fmaxf(fmaxf(f0[c], f1[c]), fmaxf(f2[c], f3[c])));
    }
    for (; i < end; ++i) {
        int s = csr[i];
        float f[8];
        ldbf<8>(X + (size_t)s * 128 + loff, f);
#pragma unroll
        for (int c = 0; c < 8; c++) acc[c] = fmaxf(acc[c], f[c]);
    }
    // inputs are post-relu (>=0): init 0 matches both running max and empty-segment rule
    uint4 v;
    v.x = f2bfbits(acc[0]) | ((uint32_t)f2bfbits(acc[1]) << 16);
    v.y = f2bfbits(acc[2]) | ((uint32_t)f2bfbits(acc[3]) << 16);
    v.z = f2bfbits(acc[4]) | ((uint32_t)f2bfbits(acc[5]) << 16);
    v.w = f2bfbits(acc[6]) | ((uint32_t)f2bfbits(acc[7]) << 16);
    *reinterpret_cast<uint4*>(out + (size_t)node * 128 + loff) = v;
}

// ---------------------- mean-aggregate(Y) + Z + LN + ReLU, 4 nodes/wave, 16B/lane ----------------------
// YZ = [N][256] bf16: cols 0-127 = Y = X@Wl, cols 128-255 = Z = X@Wr + bl.
// out[node] = ReLU(LN(mean_{s in N(node)} Y[s] + Z[node]))   [N][128] bf16
__global__ __launch_bounds__(256) void k_aggr_ln(const uint16_t* __restrict__ YZ,
                                                 const int* __restrict__ offs,
                                                 const int* __restrict__ csr,
                                                 const float* __restrict__ g,
                                                 const float* __restrict__ b,
                                                 int n, uint16_t* __restrict__ out) {
    int sl = threadIdx.x & 15;
    int node = blockIdx.x * 16 + (threadIdx.x >> 4);
    if (node >= n) return;
    int beg = offs[node], end = offs[node + 1];
    float a[8] = {};
    const size_t loff = (size_t)sl * 8;               // cols 8*sl .. 8*sl+7
    int i = beg;
    for (; i + 3 < end; i += 4) {                     // 4 rows in flight
        int s0 = csr[i], s1 = csr[i + 1], s2 = csr[i + 2], s3 = csr[i + 3];
        float f0[8], f1[8], f2[8], f3[8];
        ldbf<8>(YZ + (size_t)s0 * 256 + loff, f0);
        ldbf<8>(YZ + (size_t)s1 * 256 + loff, f1);
        ldbf<8>(YZ + (size_t)s2 * 256 + loff, f2);
        ldbf<8>(YZ + (size_t)s3 * 256 + loff, f3);
#pragma unroll
        for (int c = 0; c < 8; c++) a[c] += (f0[c] + f1[c]) + (f2[c] + f3[c]);
    }
    for (; i < end; ++i) {
        int s = csr[i];
        float f[8];
        ldbf<8>(YZ + (size_t)s * 256 + loff, f);
#pragma unroll
        for (int c = 0; c < 8; c++) a[c] += f[c];
    }
    int d = end - beg; if (d < 1) d = 1;
    float scale = 1.f / (float)d;
    float z[8];
    ldbf<8>(YZ + (size_t)node * 256 + 128 + loff, z);
    float v[8];
#pragma unroll
    for (int c = 0; c < 8; c++) v[c] = a[c] * scale + z[c];
    // LayerNorm over 128 cols (8/lane x 16 lanes); shfl stays within the 16-lane node group
    float s = 0.f, s2 = 0.f;
#pragma unroll
    for (int c = 0; c < 8; c++) { s += v[c]; s2 += v[c] * v[c]; }
#pragma unroll
    for (int o = 1; o < 16; o <<= 1) { s += __shfl_xor(s, o); s2 += __shfl_xor(s2, o); }
    float mean = s * (1.f / 128.f);
    float var = s2 * (1.f / 128.f) - mean * mean;
    float inv = rsqrtf(var + 1e-5f);
    float y[8];
#pragma unroll
    for (int c = 0; c < 8; c++)
        y[c] = fmaxf((v[c] - mean) * inv * g[loff + c] + b[loff + c], 0.f);
    uint4 w;
    w.x = f2bfbits(y[0]) | ((uint32_t)f2bfbits(y[1]) << 16);
    w.y = f2bfbits(y[2]) | ((uint32_t)f2bfbits(y[3]) << 16);
    w.z = f2bfbits(y[4]) | ((uint32_t)f2bfbits(y[5]) << 16);
    w.w = f2bfbits(y[6]) | ((uint32_t)f2bfbits(y[7]) << 16);
    *reinterpret_cast<uint4*>(out + (size_t)node * 128 + loff) = w;
}

// ---------------------- MFMA GEMM: R10 pipeline + packed-W contiguous staging ----------------------
// block = 128 rows x DB cols; 4 waves, wave = 32 rows x DB cols.
// Pipeline: stage(s) issued 2 steps ahead into lds[s%3]. Per step:
//   s_waitcnt vmcnt(L); s_barrier; sched_barrier(0); stage(s+2); ds_read + MFMA.
// W is PACKED [p][c][j] -> each W gl16 reads CONTIGUOUS 1KB.
// A frag: row=lane&15, k=(lane>>4)*8+j ; B frag: col=lane&15 ; C/D: col=lane&15, row=(lane>>4)*4+reg.
// ZBIAS: bias applied only to cols >= DOUT/2 (the Z half of a [Y|Z] dual-output GEMM).
template<int KPER, int DOUT, int DB, bool DUAL, bool LN, bool ZBIAS, typename TO>
__global__ __launch_bounds__(256) void k_mf(const uint16_t* __restrict__ A0,
                                            const uint16_t* __restrict__ A1,
                                            const uint16_t* __restrict__ WT,
                                            const float* __restrict__ bias,
                                            const float* __restrict__ g,
                                            const float* __restrict__ bvec,
                                            int n, TO* __restrict__ out) {
    constexpr int KEFF = KPER * (DUAL ? 2 : 1);
    constexpr int NST = KEFF / 32;        // k-steps
    constexpr int NF = DB / 16;
    constexpr int WPL = DB * 16;          // W plane bytes per 8-k chunk
    constexpr int AB = 8192;              // A tile bytes (128 rows x 32 k x 2B)
    constexpr int WB = DB * 64;           // W tile bytes (DB cols x 32 k x 2B)
    constexpr int HB = DB / 64;           // W 1KB-chunks per wave (1,2,4)
    constexpr int L  = 2 + HB;            // gl16 per wave per stage
    __shared__ __align__(16) uint8_t lds[3][AB + WB];

    int tid = threadIdx.x;
    int lane = tid & 63, wid = tid >> 6;
    int lr = lane & 15, kb = lane >> 4;
    int row0 = blockIdx.x * 128;
    int wrow = wid * 32;

    auto stage = [&](int kt, uint8_t* buf) {
        const uint16_t* Asel = A0; int kk = kt;
        if (DUAL && kt >= KPER) { Asel = A1; kk = kt - KPER; }
        uint8_t* aB = buf;
        uint8_t* wB = buf + AB;
        // A tile: 8 x 1KB chunks, 2 per wave (per-lane-row, 16B each)
#pragma unroll
        for (int j = 0; j < 2; ++j) {
            int p = wid * 2 + j, cb = p >> 1, h = p & 1;
            int grow = row0 + h * 64 + lane; if (grow >= n) grow = n - 1;
            gl16(Asel + (size_t)grow * KPER + kk + cb * 8, aB + cb * 2048 + h * 1024);
        }
        // W tile: packed -> contiguous 1KB per gl16
#pragma unroll
        for (int j = 0; j < HB; ++j) {
            int p = wid * HB + j, cb = p / HB, h = p % HB;
            int plane = (kt >> 3) + cb;
            gl16(WT + ((size_t)plane * DB + h * 64 + lane) * 8, wB + cb * WPL + h * 1024);
        }
    };

    f32x4 acc[2][NF] = {};
    stage(0, lds[0]);
    if constexpr (NST > 1) stage(32, lds[1]);

#pragma unroll
    for (int s = 0; s < NST; ++s) {
        if (s < NST - 1) vwait<L>(); else vwait<0>();   // own stage-s loads landed
        __builtin_amdgcn_s_barrier();                    // all waves' stage-s loads landed
        __builtin_amdgcn_sched_barrier(0);               // nothing crosses upward
        if (s + 2 < NST) stage((s + 2) * 32, lds[(s + 2) % 3]);
        const uint8_t* aB = lds[s % 3];
        const uint8_t* wB = lds[s % 3] + AB;
        bf16x8 af0 = *reinterpret_cast<const bf16x8*>(aB + kb * 2048 + (wrow + lr) * 16);
        bf16x8 af1 = *reinterpret_cast<const bf16x8*>(aB + kb * 2048 + (wrow + 16 + lr) * 16);
#pragma unroll
        for (int nf = 0; nf < NF; ++nf) {
            bf16x8 wf = *reinterpret_cast<const bf16x8*>(wB + kb * WPL + (nf * 16 + lr) * 16);
            acc[0][nf] = __builtin_amdgcn_mfma_f32_16x16x32_bf16(af0, wf, acc[0][nf], 0, 0, 0);
            acc[1][nf] = __builtin_amdgcn_mfma_f32_16x16x32_bf16(af1, wf, acc[1][nf], 0, 0, 0);
        }
    }

    // ---- epilogue: bias (+ LN + ReLU), store ----
#pragma unroll
    for (int nf = 0; nf < NF; ++nf) {
        int col = nf * 16 + lr;
        float bsv;
        if constexpr (ZBIAS) {
            bsv = (col >= DOUT / 2) ? bias[col - DOUT / 2] : 0.f;
        } else {
            bsv = (DB == DOUT || col < DOUT) ? bias[col] : 0.f;
        }
#pragma unroll
        for (int r = 0; r < 4; ++r) { acc[0][nf][r] += bsv; acc[1][nf][r] += bsv; }
    }
    if constexpr (LN) {
        float gv[NF], bv2[NF];
#pragma unroll
        for (int nf = 0; nf < NF; ++nf) {
            int col = nf * 16 + lr;
            gv[nf] = g[col]; bv2[nf] = bvec[col];
        }
#pragma unroll
        for (int m = 0; m < 2; ++m) {
            float s[4], s2[4];
#pragma unroll
            for (int r = 0; r < 4; ++r) { s[r] = 0.f; s2[r] = 0.f; }
#pragma unroll
            for (int nf = 0; nf < NF; ++nf)
#pragma unroll
                for (int r = 0; r < 4; ++r) { float v = acc[m][nf][r]; s[r] += v; s2[r] += v * v; }
#pragma unroll
            for (int r = 0; r < 4; ++r) {
#pragma unroll
                for (int o = 1; o < 16; o <<= 1) {   // xor within the 16-lane col group
                    s[r] += __shfl_xor(s[r], o);
                    s2[r] += __shfl_xor(s2[r], o);
                }
                float mean = s[r] / DOUT;
                float var = s2[r] / DOUT - mean * mean;
                float inv = rsqrtf(var + 1e-5f);
#pragma unroll
                for (int nf = 0; nf < NF; ++nf) {
                    float y = (acc[m][nf][r] - mean) * inv * gv[nf] + bv2[nf];
                    acc[m][nf][r] = fmaxf(y, 0.f);
                }
            }
        }
    }
#pragma unroll
    for (int m = 0; m < 2; ++m)
#pragma unroll
        for (int r = 0; r < 4; ++r) {
            int row = row0 + wrow + m * 16 + kb * 4 + r;
            if (row < n) {
#pragma unroll
                for (int nf = 0; nf < NF; ++nf) {
                    int col = nf * 16 + lr;
                    if (DB == DOUT || col < DOUT)
                        stv(out + (size_t)row * DOUT + col, acc[m][nf][r]);
                }
            }
        }
}

// ---------------------- fused tail: h4 = LN(relu(h3@W4+b4)); out = h4@W5 + b5 ----------------------
// W4/W5 read from PACKED layouts (contiguous gl16).
__global__ __launch_bounds__(256) void k_tail(const uint16_t* __restrict__ A,
                                              const uint16_t* __restrict__ WT4,
                                              const float* __restrict__ b4,
                                              const float* __restrict__ g4,
                                              const float* __restrict__ bv4,
                                              const uint16_t* __restrict__ WT5,
                                              const float* __restrict__ b5,
                                              int n, float* __restrict__ out) {
    __shared__ __align__(16) uint8_t lds[3][8192 + 4096];   // phase-1 pipeline (A 8KB + W4 4KB)
    __shared__ __align__(16) uint8_t w5L[16384];            // W5: 8 planes x 128 cols x 16B
    __shared__ __align__(16) uint8_t h4L[16384];            // h4: 8 k-planes x 128 rows x 16B

    int tid = threadIdx.x;
    int lane = tid & 63, wid = tid >> 6;
    int lr = lane & 15, kb = lane >> 4;
    int row0 = blockIdx.x * 128;
    int wrow = wid * 32;

    auto stage = [&](int kt, uint8_t* buf) {
        uint8_t* aB = buf;
        uint8_t* wB = buf + 8192;
#pragma unroll
        for (int j = 0; j < 2; ++j) {
            int p = wid * 2 + j, cb = p >> 1, h = p & 1;
            int grow = row0 + h * 64 + lane; if (grow >= n) grow = n - 1;
            gl16(A + (size_t)grow * 128 + kt + cb * 8, aB + cb * 2048 + h * 1024);
        }
        // W4 packed: plane (kt/8 + wid), cols 0..63 -> contiguous 1KB
        gl16(WT4 + ((size_t)((kt >> 3) + wid) * 64 + lane) * 8, wB + wid * 1024);
    };

    // stage ALL of W5 first (packed; 4 contiguous-1KB chunks per wave)
#pragma unroll
    for (int j = 0; j < 4; ++j) {
        int p = wid * 4 + j, cb = p >> 1, h = p & 1;
        gl16(WT5 + ((size_t)cb * 128 + h * 64 + lane) * 8, w5L + cb * 2048 + h * 1024);
    }

    f32x4 acc1[2][4] = {};
    stage(0, lds[0]);
    stage(32, lds[1]);

#pragma unroll
    for (int s = 0; s < 4; ++s) {
        if (s < 3) vwait<3>(); else vwait<0>();
        __builtin_amdgcn_s_barrier();
        __builtin_amdgcn_sched_barrier(0);
        if (s + 2 < 4) stage((s + 2) * 32, lds[(s + 2) % 3]);
        const uint8_t* aB = lds[s % 3];
        const uint8_t* wB = lds[s % 3] + 8192;
        bf16x8 af0 = *reinterpret_cast<const bf16x8*>(aB + kb * 2048 + (wrow + lr) * 16);
        bf16x8 af1 = *reinterpret_cast<const bf16x8*>(aB + kb * 2048 + (wrow + 16 + lr) * 16);
#pragma unroll
        for (int nf = 0; nf < 4; ++nf) {
            bf16x8 wf = *reinterpret_cast<const bf16x8*>(wB + kb * 1024 + (nf * 16 + lr) * 16);
            acc1[0][nf] = __builtin_amdgcn_mfma_f32_16x16x32_bf16(af0, wf, acc1[0][nf], 0, 0, 0);
            acc1[1][nf] = __builtin_amdgcn_mfma_f32_16x16x32_bf16(af1, wf, acc1[1][nf], 0, 0, 0);
        }
    }

    // ---- bias + per-wave LN + ReLU (DOUT=64) ----
#pragma unroll
    for (int nf = 0; nf < 4; ++nf) {
        float bsv = b4[nf * 16 + lr];
#pragma unroll
        for (int r = 0; r < 4; ++r) { acc1[0][nf][r] += bsv; acc1[1][nf][r] += bsv; }
    }
    {
        float gv[4], bv2[4];
#pragma unroll
        for (int nf = 0; nf < 4; ++nf) { gv[nf] = g4[nf * 16 + lr]; bv2[nf] = bv4[nf * 16 + lr]; }
#pragma unroll
        for (int m = 0; m < 2; ++m) {
            float s[4] = {}, s2[4] = {};
#pragma unroll
            for (int nf = 0; nf < 4; ++nf)
#pragma unroll
                for (int r = 0; r < 4; ++r) { float v = acc1[m][nf][r]; s[r] += v; s2[r] += v * v; }
#pragma unroll
            for (int r = 0; r < 4; ++r) {
#pragma unroll
                for (int o = 1; o < 16; o <<= 1) { s[r] += __shfl_xor(s[r], o); s2[r] += __shfl_xor(s2[r], o); }
                float mean = s[r] * (1.f / 64.f);
                float var = s2[r] * (1.f / 64.f) - mean * mean;
                float inv = rsqrtf(var + 1e-5f);
#pragma unroll
                for (int nf = 0; nf < 4; ++nf)
                    acc1[m][nf][r] = fmaxf((acc1[m][nf][r] - mean) * inv * gv[nf] + bv2[nf], 0.f);
            }
        }
    }

    // ---- transpose h4 into A-fragment planes ----
#pragma unroll
    for (int m = 0; m < 2; ++m)
#pragma unroll
        for (int r = 0; r < 4; ++r) {
            int row = wrow + m * 16 + kb * 4 + r;
#pragma unroll
            for (int nf = 0; nf < 4; ++nf) {
                int col = nf * 16 + lr;
                *reinterpret_cast<uint16_t*>(h4L + ((col >> 3) * 2048 + row * 16 + (col & 7) * 2)) =
                    f2bfbits(acc1[m][nf][r]);
            }
        }
    __syncthreads();

    // ---- phase 2: out = h4 @ W5 + b5 (K=64, 2 steps, all LDS-resident) ----
    f32x4 acc2[2][8] = {};
#pragma unroll
    for (int s = 0; s < 2; ++s) {
        bf16x8 af0 = *reinterpret_cast<const bf16x8*>(h4L + (s * 4 + kb) * 2048 + (wrow + lr) * 16);
        bf16x8 af1 = *reinterpret_cast<const bf16x8*>(h4L + (s * 4 + kb) * 2048 + (wrow + 16 + lr) * 16);
#pragma unroll
        for (int nf = 0; nf < 8; ++nf) {
            bf16x8 wf = *reinterpret_cast<const bf16x8*>(w5L + (s * 4 + kb) * 2048 + (nf * 16 + lr) * 16);
            acc2[0][nf] = __builtin_amdgcn_mfma_f32_16x16x32_bf16(af0, wf, acc2[0][nf], 0, 0, 0);
            acc2[1][nf] = __builtin_amdgcn_mfma_f32_16x16x32_bf16(af1, wf, acc2[1][nf], 0, 0, 0);
        }
    }
#pragma unroll
    for (int m = 0; m < 2; ++m)
#pragma unroll
        for (int r = 0; r < 4; ++r) {
            int row = row0 + wrow + m * 16 + kb * 4 + r;
            if (row < n) {
#pragma unroll
                for (int nf = 0; nf < 8; ++nf) {
                    int col = nf * 16 + lr;
                    if (col < 100)
                        out[(size_t)row * 100 + col] = acc2[m][nf][r] + b5[col];
                }
            }
        }
}

// ---------------------- launcher ----------------------
extern "C" void kernel_launch(void* const* d_in, const int* in_sizes, int n_in,
                              void* d_out, int out_size, void* d_ws, size_t ws_size,
                              hipStream_t stream) {
    const float* x     = (const float*)d_in[0];
    const int*   src   = (const int*)d_in[1];
    const int*   dst   = (const int*)d_in[2];
    const float* s1_wl = (const float*)d_in[3];
    const float* s1_bl = (const float*)d_in[4];
    const float* s1_wr = (const float*)d_in[5];
    const float* ln1_g = (const float*)d_in[6];
    const float* ln1_b = (const float*)d_in[7];
    const float* s2_wl = (const float*)d_in[8];
    const float* s2_bl = (const float*)d_in[9];
    const float* s2_wr = (const float*)d_in[10];
    const float* ln2_g = (const float*)d_in[11];
    const float* ln2_b = (const float*)d_in[12];
    const float* s3_wl = (const float*)d_in[13];
    const float* s3_bl = (const float*)d_in[14];
    const float* s3_wr = (const float*)d_in[15];
    const float* ln3_g = (const float*)d_in[16];
    const float* ln3_b = (const float*)d_in[17];
    const float* l1_w  = (const float*)d_in[18];
    const float* l1_b  = (const float*)d_in[19];
    const float* ln4_g = (const float*)d_in[20];
    const float* ln4_b = (const float*)d_in[21];
    const float* lo_w  = (const float*)d_in[22];
    const float* lo_b  = (const float*)d_in[23];
    float* out = (float*)d_out;

    const int N = in_sizes[0] / 128;
    const int E = in_sizes[1];
    (void)n_in; (void)out_size; (void)ws_size;

    char* w = (char*)d_ws;
    size_t off = 0;
    auto alloc = [&](size_t bytes) -> void* {
        void* p = w + off;
        off = (off + bytes + 255) & ~(size_t)255;
        return p;
    };
    int* deg    = (int*)alloc((size_t)N * 4);
    int* offs   = (int*)alloc((size_t)(N + 1) * 4);
    int* cursor = (int*)alloc((size_t)N * 4);
    int* bsum   = (int*)alloc(1024 * 4);
    int* csr    = (int*)alloc((size_t)E * 4);
    uint16_t* wt1 = (uint16_t*)alloc(256 * 128 * 2);   // packed [16 planes][256 cols][8]
    uint16_t* wt2 = (uint16_t*)alloc(256 * 256 * 2);   // packed [32 planes][256 cols][8]
    uint16_t* wt3 = (uint16_t*)alloc(256 * 256 * 2);   // packed [32 planes][256 cols][8]
    uint16_t* wt4 = (uint16_t*)alloc(64 * 128 * 2);    // packed [16 planes][64 cols][8]
    uint16_t* wt5 = (uint16_t*)alloc(128 * 64 * 2);    // packed [8 planes][128 cols][8]
    uint16_t* xb    = (uint16_t*)alloc((size_t)N * 128 * 2);
    uint16_t* YZ    = (uint16_t*)alloc((size_t)N * 256 * 2);  // [Y|Z] for layers 1 and 3
    uint16_t* h1    = (uint16_t*)alloc((size_t)N * 128 * 2);
    uint16_t* aggrB = (uint16_t*)alloc((size_t)N * 128 * 2);  // max-aggr output
    uint16_t* h2    = (uint16_t*)alloc((size_t)N * 256 * 2);
    uint16_t* h3    = (uint16_t*)alloc((size_t)N * 128 * 2);

    int gE = (E + 255) / 256;
    int nb = (N + 1023) / 1024;
    int gN16 = (N + 15) / 16;
    int g128 = (N + 127) / 128;

    // CSR build
    hipMemsetAsync(deg, 0, (size_t)N * 4, stream);
    k_count<<<gE, 256, 0, stream>>>(dst, E, deg);
    k_block_sums<<<nb, 256, 0, stream>>>(deg, N, bsum);
    k_scan_bsums<<<1, 256, 0, stream>>>(bsum, nb);
    k_scan_final<<<nb, 256, 0, stream>>>(deg, N, bsum, offs, cursor);
    k_scatter<<<gE, 256, 0, stream>>>(src, dst, E, cursor, csr);

    // fused weight prep (packed layout)
    PrepAll P;
    int cum = 0;
    auto seg = [&](int i, const float* W, uint16_t* wt, int K, int Dreal, int ncols,
                   int koff, int noff, int Dtot) {
        P.s[i] = {W, wt, K, Dreal, ncols, koff, noff, Dtot, cum, cum + ncols * K};
        cum += ncols * K;
    };
    seg(0, s1_wl, wt1, 128, 128, 128, 0,   0,   256);
    seg(1, s1_wr, wt1, 128, 128, 128, 0,   128, 256);
    seg(2, s2_wl, wt2, 128, 256, 256, 0,   0,   256);
    seg(3, s2_wr, wt2, 128, 256, 256, 128, 0,   256);
    seg(4, s3_wl, wt3, 256, 128, 128, 0,   0,   256);
    seg(5, s3_wr, wt3, 256, 128, 128, 0,   128, 256);
    seg(6, l1_w,  wt4, 128, 64,  64,  0,   0,   64);
    seg(7, lo_w,  wt5, 64,  100, 128, 0,   0,   128);
    k_prep_all<<<(cum + 255) / 256, 256, 0, stream>>>(P, cum);

    // x -> bf16
    k_f2b<<<(N * 128 / 4 + 255) / 256, 256, 0, stream>>>(x, xb, N * 128 / 4);

    // layer 1 (mean, reordered): YZ1 = xb @ [Wl1|Wr1] (+bl on Z half); h1 = LN(mean(Y1)+Z1)
    k_mf<128, 256, 256, false, false, true, uint16_t><<<g128, 256, 0, stream>>>(
        xb, nullptr, wt1, s1_bl, nullptr, nullptr, N, YZ);
    k_aggr_ln<<<gN16, 256, 0, stream>>>(YZ, offs, csr, ln1_g, ln1_b, N, h1);

    // layer 2 (max): aggrB = max-gather(h1); h2 = LN([aggrB|h1] @ wt2 + b2)
    k_aggr_max<<<gN16, 256, 0, stream>>>(h1, offs, csr, N, aggrB);
    k_mf<128, 256, 256, true, true, false, uint16_t><<<g128, 256, 0, stream>>>(
        aggrB, h1, wt2, s2_bl, ln2_g, ln2_b, N, h2);

    // layer 3 (mean, reordered): YZ3 = h2 @ [Wl3|Wr3] (+bl on Z half); h3 = LN(mean(Y3)+Z3)
    k_mf<256, 256, 256, false, false, true, uint16_t><<<g128, 256, 0, stream>>>(
        h2, nullptr, wt3, s3_bl, nullptr, nullptr, N, YZ);
    k_aggr_ln<<<gN16, 256, 0, stream>>>(YZ, offs, csr, ln3_g, ln3_b, N, h3);

    // fused tail: lin1 + LN + ReLU + output projection (fp32 out)
    k_tail<<<g128, 256, 0, stream>>>(h3, wt4, l1_b, ln4_g, ln4_b, wt5, lo_b, N, out);
}